// Round 17
// baseline (277.412 us; speedup 1.0000x reference)
//
#include <hip/hip_runtime.h>

#define N_USERS 100000
#define N_ITEMS 50000
#define N_NODES 150000
#define N_EDGES 2400000
#define EMB 64
#define LEAKY 0.3f

#define RB_SHIFT 7                                         // 128 rows / bucket
#define RB (1 << RB_SHIFT)
#define NBKT ((N_NODES + RB - 1) >> RB_SHIFT)              // 1172
#define L1_CHUNK 16384
#define NCH ((N_EDGES + L1_CHUNK - 1) / L1_CHUNK)          // 147 chunks
#define SCAN_ITEMS ((NBKT + 1023) / 1024)                  // 2
#define COL_MASK 0x3FFFFu                                  // col < 2^18
#define NTILE (N_NODES / 16)                               // 9375 (exact)

typedef unsigned short u16;
typedef unsigned int   u32;
typedef __attribute__((ext_vector_type(8))) short short8v;
typedef __attribute__((ext_vector_type(4))) float f32x4;
typedef __attribute__((ext_vector_type(2))) float v2f;

__device__ __forceinline__ u16 f32_to_bf16_rne(float f) {
    u32 u = __float_as_uint(f);
    u32 r = (u + 0x7FFFu + ((u >> 16) & 1u)) >> 16;
    return (u16)r;
}
__device__ __forceinline__ float bf16_lo(u32 x) { return __uint_as_float(x << 16); }
__device__ __forceinline__ u32 pack_bf16(float lo, float hi) {
    return (u32)f32_to_bf16_rne(lo) | ((u32)f32_to_bf16_rne(hi) << 16);
}
// unpack a bf16-pair dword into a packed f32 pair (feeds v_pk_fma_f32)
__device__ __forceinline__ v2f up2(u32 w) {
    v2f r;
    r.x = __uint_as_float(w << 16);
    r.y = __uint_as_float(w & 0xFFFF0000u);
    return r;
}

// ===========================================================================
// e0 -> bf16 (user ++ item) and W0/W1 -> bf16, one dispatch
// ===========================================================================
__global__ __launch_bounds__(256) void conv_all(
    const float* __restrict__ uemb, const float* __restrict__ iemb,
    const float* __restrict__ W0, const float* __restrict__ W1,
    u16* __restrict__ ebf, u16* __restrict__ Wbf0, u16* __restrict__ Wbf1)
{
    const int gid = blockIdx.x * 256 + threadIdx.x;
    const int i = gid * 4;
    if (i < N_NODES * EMB) {
        const float* src = (i < N_USERS * EMB) ? uemb + i : iemb + (i - N_USERS * EMB);
        const float4 v = *(const float4*)src;
        ushort4 w;
        w.x = f32_to_bf16_rne(v.x);
        w.y = f32_to_bf16_rne(v.y);
        w.z = f32_to_bf16_rne(v.z);
        w.w = f32_to_bf16_rne(v.w);
        *(ushort4*)(ebf + i) = w;
    }
    if (gid < EMB * EMB) {
        Wbf0[gid] = f32_to_bf16_rne(W0[gid]);
        Wbf1[gid] = f32_to_bf16_rne(W1[gid]);
    }
}

// ===========================================================================
// Per-chunk bucket histogram -> H[chunk][NBKT] (no global atomics)
// ===========================================================================
__global__ __launch_bounds__(1024) void bkt_hist(
    const int* __restrict__ rows, int* __restrict__ H)
{
    __shared__ int cnt[NBKT];
    const int t = threadIdx.x;
    const int c = blockIdx.x;
    for (int b = t; b < NBKT; b += 1024) cnt[b] = 0;
    __syncthreads();

    const int e0 = c * L1_CHUNK;
    const int e1 = (e0 + L1_CHUNK < N_EDGES) ? e0 + L1_CHUNK : N_EDGES;
    for (int i = e0 + t; i < e1; i += 1024)
        atomicAdd(&cnt[rows[i] >> RB_SHIFT], 1);
    __syncthreads();

    for (int b = t; b < NBKT; b += 1024) H[c * NBKT + b] = cnt[b];
}

// ===========================================================================
// scan_plus (single block): bucket totals -> bkt_ptr; B[c][b] bases.
// ===========================================================================
__global__ __launch_bounds__(1024) void scan_plus(
    const int* __restrict__ H, int* __restrict__ bkt_ptr,
    int* __restrict__ B)
{
    __shared__ int lds[1024];
    const int t = threadIdx.x;

    int v[SCAN_ITEMS];
    int s = 0;
    #pragma unroll
    for (int j = 0; j < SCAN_ITEMS; ++j) {
        const int idx = t * SCAN_ITEMS + j;
        int tot = 0;
        if (idx < NBKT) {
            int c = 0;
            int s0 = 0, s1 = 0, s2 = 0, s3 = 0;
            for (; c + 4 <= NCH; c += 4) {
                s0 += H[(c + 0) * NBKT + idx];
                s1 += H[(c + 1) * NBKT + idx];
                s2 += H[(c + 2) * NBKT + idx];
                s3 += H[(c + 3) * NBKT + idx];
            }
            for (; c < NCH; ++c) s0 += H[c * NBKT + idx];
            tot = (s0 + s1) + (s2 + s3);
        }
        v[j] = tot;
        s += tot;
    }
    lds[t] = s;
    __syncthreads();
    for (int off = 1; off < 1024; off <<= 1) {
        int x = 0;
        if (t >= off) x = lds[t - off];
        __syncthreads();
        lds[t] += x;
        __syncthreads();
    }
    int run = lds[t] - s;   // exclusive prefix of this thread's group

    #pragma unroll
    for (int j = 0; j < SCAN_ITEMS; ++j) {
        const int idx = t * SCAN_ITEMS + j;
        if (idx < NBKT) {
            bkt_ptr[idx] = run;
            int r2 = run;
            for (int c = 0; c < NCH; ++c) {
                B[c * NBKT + idx] = r2;
                r2 += H[c * NBKT + idx];
            }
            run += v[j];
        }
    }
    if (t == 0) bkt_ptr[NBKT] = N_EDGES;
}

// ===========================================================================
// Partition (single edge pass, no global atomics)
// record = (val, (localrow<<18)|col), localrow 7 bits
// ===========================================================================
__global__ __launch_bounds__(1024) void partition_l1(
    const float* __restrict__ vals, const int* __restrict__ rows,
    const int* __restrict__ cols, const int* __restrict__ B,
    float2* __restrict__ svc)
{
    __shared__ int base[NBKT];
    __shared__ int cnt[NBKT];
    const int t = threadIdx.x;
    const int c = blockIdx.x;
    for (int b = t; b < NBKT; b += 1024) {
        base[b] = B[c * NBKT + b];
        cnt[b]  = 0;
    }
    __syncthreads();

    const int e0 = c * L1_CHUNK;
    const int e1 = (e0 + L1_CHUNK < N_EDGES) ? e0 + L1_CHUNK : N_EDGES;
    for (int i = e0 + t; i < e1; i += 1024) {
        const int r = rows[i];
        const int b = r >> RB_SHIFT;
        const int pos = base[b] + atomicAdd(&cnt[b], 1);
        const u32 packed = ((u32)(r & (RB - 1)) << 18) | (u32)cols[i];
        svc[pos] = make_float2(vals[i], __uint_as_float(packed));
    }
}

// ===========================================================================
// place_l2: per-row count (LDS) -> LDS scan -> row_ptr -> in-bucket
// placement via LDS heads. RB=128 -> 1172 blocks (2x TLP). PLAIN stores:
// block's writes stay in a ~16KB range so one XCD L2 assembles full lines.
// ===========================================================================
__global__ __launch_bounds__(256) void place_l2(
    const int* __restrict__ bkt_ptr, const float2* __restrict__ svc,
    float2* __restrict__ sedge, int* __restrict__ row_ptr)
{
    __shared__ int cnt[RB];
    __shared__ int heads[RB];
    const int b     = blockIdx.x;
    const int rbase = b << RB_SHIFT;
    const int t     = threadIdx.x;

    if (t < RB) cnt[t] = 0;
    __syncthreads();

    const int lo = bkt_ptr[b];
    const int hi = bkt_ptr[b + 1];

    for (int i = lo + t; i < hi; i += 256)
        atomicAdd(&cnt[__float_as_uint(svc[i].y) >> 18], 1);
    __syncthreads();

    int v = 0;
    if (t < RB) v = cnt[t];
    for (int off = 1; off < RB; off <<= 1) {
        int x = 0;
        if (t < RB && t >= off) x = cnt[t - off];
        __syncthreads();
        if (t < RB) cnt[t] += x;
        __syncthreads();
    }
    if (t < RB) {
        const int excl = cnt[t] - v;
        heads[t] = lo + excl;
        const int gr = rbase + t;
        if (gr <= N_NODES) row_ptr[gr] = lo + excl;
    }
    __syncthreads();

    for (int i = lo + t; i < hi; i += 256) {
        const float2 vc = svc[i];
        const int lr  = (int)(__float_as_uint(vc.y) >> 18);
        const int pos = atomicAdd(&heads[lr], 1);
        sedge[pos] = vc;
    }
}

// ===========================================================================
// Pull-SpMM over bf16 source (round-16 proven): dwordx4 gather, single
// predicated 16-wide loop, packed v2f accumulate (v_pk_fma_f32).
// ===========================================================================
__global__ __launch_bounds__(256) void spmm_bf16(
    const int* __restrict__ row_ptr,     // N_NODES+1
    const float2* __restrict__ sedge,    // (val, packed) row-sorted
    const u16* __restrict__ ebf,         // [N_NODES][64] bf16
    u16* __restrict__ tbf)               // [N_NODES][64] bf16
{
    const int tid  = threadIdx.x;
    const int lane = tid & 63;
    const int row  = blockIdx.x * 4 + (tid >> 6);
    if (row >= N_NODES) return;

    const int g = lane >> 3;    // edge slot 0..7
    const int q = lane & 7;     // feature octet -> features 8q..8q+7

    const int beg = row_ptr[row];
    const int end = row_ptr[row + 1];

    v2f A0 = {0.f, 0.f}, A1 = {0.f, 0.f}, A2 = {0.f, 0.f}, A3 = {0.f, 0.f};

    for (int k = beg; k < end; k += 16) {
        const int  kA  = k + g;
        const int  kB  = k + 8 + g;
        const bool onA = kA < end;
        const bool onB = kB < end;
        const float2 mA = sedge[onA ? kA : end - 1];
        const float2 mB = sedge[onB ? kB : end - 1];
        const float vA = onA ? mA.x : 0.f;
        const float vB = onB ? mB.x : 0.f;
        const u32 iA = __float_as_uint(mA.y) & COL_MASK;
        const u32 iB = __float_as_uint(mB.y) & COL_MASK;
        const uint4 xA = *((const uint4*)(ebf + (size_t)iA * EMB) + q);
        const uint4 xB = *((const uint4*)(ebf + (size_t)iB * EMB) + q);
        const v2f vvA = {vA, vA};
        const v2f vvB = {vB, vB};
        A0 = vvA * up2(xA.x) + A0;
        A1 = vvA * up2(xA.y) + A1;
        A2 = vvA * up2(xA.z) + A2;
        A3 = vvA * up2(xA.w) + A3;
        A0 = vvB * up2(xB.x) + A0;
        A1 = vvB * up2(xB.y) + A1;
        A2 = vvB * up2(xB.z) + A2;
        A3 = vvB * up2(xB.w) + A3;
    }

    // reduce across the 8 edge slots (xor 8,16,32) per f32 component
    float s0 = A0.x, s1 = A0.y, s2 = A1.x, s3 = A1.y;
    float s4 = A2.x, s5 = A2.y, s6 = A3.x, s7 = A3.y;
    s0 += __shfl_xor(s0, 8); s0 += __shfl_xor(s0, 16); s0 += __shfl_xor(s0, 32);
    s1 += __shfl_xor(s1, 8); s1 += __shfl_xor(s1, 16); s1 += __shfl_xor(s1, 32);
    s2 += __shfl_xor(s2, 8); s2 += __shfl_xor(s2, 16); s2 += __shfl_xor(s2, 32);
    s3 += __shfl_xor(s3, 8); s3 += __shfl_xor(s3, 16); s3 += __shfl_xor(s3, 32);
    s4 += __shfl_xor(s4, 8); s4 += __shfl_xor(s4, 16); s4 += __shfl_xor(s4, 32);
    s5 += __shfl_xor(s5, 8); s5 += __shfl_xor(s5, 16); s5 += __shfl_xor(s5, 32);
    s6 += __shfl_xor(s6, 8); s6 += __shfl_xor(s6, 16); s6 += __shfl_xor(s6, 32);
    s7 += __shfl_xor(s7, 8); s7 += __shfl_xor(s7, 16); s7 += __shfl_xor(s7, 32);

    if (g == 0) {
        uint4 w;
        w.x = pack_bf16(s0, s1);
        w.y = pack_bf16(s2, s3);
        w.z = pack_bf16(s4, s5);
        w.w = pack_bf16(s6, s7);
        *(uint4*)(tbf + (size_t)row * EMB + 8 * q) = w;
    }
}

// ===========================================================================
// Dense stage via MFMA: e1 = t @ W^T fused with LeakyReLU + mean-accum.
// FIRST: obf = bf16(0.25*(e0+e1+e2)), e2 -> ebf.  (no f32 out traffic)
// !FIRST: out = f32(obf) + 0.25*e3   (single f32 write of d_out)
// ===========================================================================
template <bool FIRST>
__global__ __launch_bounds__(256) void dense_mfma(
    const u16* __restrict__ tbf,     // [N_NODES][64] bf16
    const u16* __restrict__ Wbf,     // [64][64] bf16
    u16* ebf,                        // FIRST: e0 read + e2 write (same elem)
    u16* __restrict__ obf,           // partial mean, bf16
    float* __restrict__ out)
{
    const int tid  = threadIdx.x;
    const int l    = tid & 63;
    const int tile = blockIdx.x * 4 + (tid >> 6);
    if (tile >= NTILE) return;
    const int row0 = tile * 16;

    const int lr = l & 15;
    const int lk = l >> 4;

    short8v bfrag[4][2];
    #pragma unroll
    for (int c = 0; c < 4; ++c)
        #pragma unroll
        for (int kh = 0; kh < 2; ++kh)
            bfrag[c][kh] = *(const short8v*)(Wbf + (size_t)(16 * c + lr) * EMB
                                             + 32 * kh + 8 * lk);

    const u16* trow = tbf + (size_t)(row0 + lr) * EMB;
    const short8v afrag0 = *(const short8v*)(trow + 8 * lk);
    const short8v afrag1 = *(const short8v*)(trow + 32 + 8 * lk);

    f32x4 acc[4];
    #pragma unroll
    for (int c = 0; c < 4; ++c) {
        f32x4 z = {0.f, 0.f, 0.f, 0.f};
        z = __builtin_amdgcn_mfma_f32_16x16x32_bf16(afrag0, bfrag[c][0], z, 0, 0, 0);
        z = __builtin_amdgcn_mfma_f32_16x16x32_bf16(afrag1, bfrag[c][1], z, 0, 0, 0);
        acc[c] = z;
    }

    #pragma unroll
    for (int c = 0; c < 4; ++c) {
        #pragma unroll
        for (int r = 0; r < 4; ++r) {
            const int row = row0 + 4 * lk + r;
            const size_t idx = (size_t)row * EMB + 16 * c + lr;
            const float e1v = acc[c][r];
            if (FIRST) {
                const float e2v = (e1v >= 0.f) ? e1v : LEAKY * e1v;
                const float e0v = bf16_lo((u32)ebf[idx]);   // e0 (bf16)
                obf[idx] = f32_to_bf16_rne(0.25f * (e0v + e1v + e2v));
                ebf[idx] = f32_to_bf16_rne(e2v);            // e2 for stage 2
            } else {
                out[idx] = bf16_lo((u32)obf[idx]) + 0.25f * e1v;
            }
        }
    }
}

// ===========================================================================
// Fallback (round-1 proven): atomic SpMM + f32 dense, if ws too small.
// ===========================================================================
__global__ __launch_bounds__(256) void spmm_atomic(
    const float* __restrict__ vals, const int* __restrict__ rows,
    const int* __restrict__ cols, const float* __restrict__ src_a,
    const float* __restrict__ src_b, float* __restrict__ dst)
{
    const int tid  = threadIdx.x;
    const int lane = tid & 63;
    const int e    = blockIdx.x * 4 + (tid >> 6);
    if (e >= N_EDGES) return;
    const float v = vals[e];
    const int   c = cols[e];
    const int   r = rows[e];
    const float* src = (src_b != nullptr && c >= N_USERS)
                           ? src_b + (size_t)(c - N_USERS) * EMB
                           : src_a + (size_t)c * EMB;
    unsafeAtomicAdd(&dst[(size_t)r * EMB + lane], v * src[lane]);
}

template <bool FIRST>
__global__ __launch_bounds__(256) void dense_f32(
    const float* __restrict__ t, const float* __restrict__ W,
    const float* __restrict__ user_emb, const float* __restrict__ item_emb,
    float* __restrict__ e2, float* __restrict__ out)
{
    __shared__ float wT[64][65];
    __shared__ float trow[16][64];

    const int tid = threadIdx.x;
    for (int k = tid; k < 64 * 64; k += 256) {
        const int i = k >> 6, j = k & 63;
        wT[j][i] = W[k];
    }
    const int row_base = blockIdx.x * 16;
    for (int k = tid; k < 16 * 64; k += 256) {
        const int r = k >> 6, j = k & 63;
        const int row = row_base + r;
        trow[r][j] = (row < N_NODES) ? t[(size_t)row * EMB + j] : 0.f;
    }
    __syncthreads();

    const int i  = tid & 63;
    const int r0 = tid >> 6;

    #pragma unroll
    for (int rr = 0; rr < 4; ++rr) {
        const int r   = r0 * 4 + rr;
        const int row = row_base + r;
        if (row >= N_NODES) continue;
        float acc = 0.f;
        #pragma unroll
        for (int j = 0; j < 64; ++j)
            acc = fmaf(trow[r][j], wT[j][i], acc);
        const size_t idx = (size_t)row * EMB + i;
        if (FIRST) {
            const float e1v = acc;
            const float e2v = (e1v >= 0.f) ? e1v : LEAKY * e1v;
            const float e0v = (row < N_USERS)
                                  ? user_emb[idx]
                                  : item_emb[(size_t)(row - N_USERS) * EMB + i];
            e2[idx]  = e2v;
            out[idx] = 0.25f * (e0v + e1v + e2v);
        } else {
            out[idx] += 0.25f * acc;
        }
    }
}

// ===========================================================================
extern "C" void kernel_launch(void* const* d_in, const int* in_sizes, int n_in,
                              void* d_out, int out_size, void* d_ws, size_t ws_size,
                              hipStream_t stream)
{
    const float* user_emb = (const float*)d_in[0];
    const float* item_emb = (const float*)d_in[1];
    const float* W0       = (const float*)d_in[2];
    const float* W1       = (const float*)d_in[3];
    const float* adj_vals = (const float*)d_in[4];
    const int*   adj_rows = (const int*)d_in[5];
    const int*   adj_cols = (const int*)d_in[6];
    float*       out      = (float*)d_out;

    const size_t mat_bytes = (size_t)N_NODES * EMB * sizeof(float);   // 38.4 MB
    const size_t ebf_bytes = (size_t)N_NODES * EMB * sizeof(u16);     // 19.2 MB
    const size_t edge8     = (size_t)N_EDGES * sizeof(float2);        // 19.2 MB
    const size_t hmat      = (size_t)NCH * NBKT * sizeof(int);        // 0.69 MB

    // layout: [tbf | svc transient] [sedge] [ebf] [obf] [aux] [Wbf]
    const size_t off_tbf    = 0;
    const size_t off_svc    = 0;                       // transient, inside tbf
    const size_t off_sedge  = off_tbf + ebf_bytes;
    const size_t off_ebf    = off_sedge + edge8;
    const size_t off_obf    = off_ebf + ebf_bytes;
    const size_t off_rowptr = off_obf + ebf_bytes;
    const size_t off_H      = off_rowptr + (size_t)(N_NODES + 1) * sizeof(int);
    const size_t off_B      = off_H + hmat;
    const size_t off_ptr    = off_B + hmat;
    const size_t off_wbf    = (off_ptr + (size_t)(NBKT + 1) * sizeof(int) + 15) & ~(size_t)15;
    const size_t required   = off_wbf + 2 * (size_t)EMB * EMB * sizeof(u16); // ~79.5 MB

    const int spmm_blocks   = (N_NODES + 3) / 4;       // 37500
    const int densem_blocks = (NTILE + 3) / 4;         // 2344
    const int conv_blocks   = (N_NODES * EMB / 4 + 255) / 256;

    if (ws_size >= required) {
        u16*    tbf     = (u16*)((char*)d_ws + off_tbf);
        float2* svc     = (float2*)((char*)d_ws + off_svc);
        float2* sedge   = (float2*)((char*)d_ws + off_sedge);
        u16*    ebf     = (u16*)((char*)d_ws + off_ebf);
        u16*    obf     = (u16*)((char*)d_ws + off_obf);
        int*    row_ptr = (int*)((char*)d_ws + off_rowptr);
        int*    H       = (int*)((char*)d_ws + off_H);
        int*    B       = (int*)((char*)d_ws + off_B);
        int*    bkt_ptr = (int*)((char*)d_ws + off_ptr);
        u16*    Wbf0    = (u16*)((char*)d_ws + off_wbf);
        u16*    Wbf1    = Wbf0 + EMB * EMB;

        // ---- bf16 sources (e0, W0, W1) ----
        conv_all<<<conv_blocks, 256, 0, stream>>>(
            user_emb, item_emb, W0, W1, ebf, Wbf0, Wbf1);

        // ---- bucket-sorted edge list + row_ptr (once, reused twice) ----
        bkt_hist<<<NCH, 1024, 0, stream>>>(adj_rows, H);
        scan_plus<<<1, 1024, 0, stream>>>(H, bkt_ptr, B);
        partition_l1<<<NCH, 1024, 0, stream>>>(
            adj_vals, adj_rows, adj_cols, B, svc);
        place_l2<<<NBKT, 256, 0, stream>>>(bkt_ptr, svc, sedge, row_ptr);
        // svc (inside tbf) is dead from here on

        // ---- stage 1: tbf = A @ e0 ; obf = 0.25(e0+e1+e2) ; e2 -> ebf ----
        spmm_bf16<<<spmm_blocks, 256, 0, stream>>>(row_ptr, sedge, ebf, tbf);
        dense_mfma<true><<<densem_blocks, 256, 0, stream>>>(
            tbf, Wbf0, ebf, obf, out);

        // ---- stage 2: tbf = A @ e2 ; out = obf + 0.25*e3 ----
        spmm_bf16<<<spmm_blocks, 256, 0, stream>>>(row_ptr, sedge, ebf, tbf);
        dense_mfma<false><<<densem_blocks, 256, 0, stream>>>(
            tbf, Wbf1, ebf, obf, out);
    } else {
        // ---- fallback: round-1 atomic path ----
        float* t  = (float*)d_ws;
        float* e2 = (float*)((char*)d_ws + mat_bytes);
        const int dense_blocks = (N_NODES + 15) / 16;

        hipMemsetAsync(t, 0, mat_bytes, stream);
        spmm_atomic<<<(N_EDGES + 3) / 4, 256, 0, stream>>>(
            adj_vals, adj_rows, adj_cols, user_emb, item_emb, t);
        dense_f32<true><<<dense_blocks, 256, 0, stream>>>(
            t, W0, user_emb, item_emb, e2, out);

        hipMemsetAsync(t, 0, mat_bytes, stream);
        spmm_atomic<<<(N_EDGES + 3) / 4, 256, 0, stream>>>(
            adj_vals, adj_rows, adj_cols, e2, nullptr, t);
        dense_f32<false><<<dense_blocks, 256, 0, stream>>>(
            t, W1, nullptr, nullptr, nullptr, out);
    }
}

// Round 18
// 275.339 us; speedup vs baseline: 1.0075x; 1.0075x over previous
//
#include <hip/hip_runtime.h>

#define N_USERS 100000
#define N_ITEMS 50000
#define N_NODES 150000
#define N_EDGES 2400000
#define EMB 64
#define LEAKY 0.3f

#define RB_SHIFT 7                                         // 128 rows / bucket
#define RB (1 << RB_SHIFT)
#define NBKT ((N_NODES + RB - 1) >> RB_SHIFT)              // 1172
#define L1_CHUNK 16384
#define NCH ((N_EDGES + L1_CHUNK - 1) / L1_CHUNK)          // 147 chunks
#define SCAN_ITEMS ((NBKT + 1023) / 1024)                  // 2
#define COL_MASK 0x3FFFFu                                  // col < 2^18
#define NTILE (N_NODES / 16)                               // 9375 (exact)

typedef unsigned short u16;
typedef unsigned int   u32;
typedef __attribute__((ext_vector_type(8))) short short8v;
typedef __attribute__((ext_vector_type(4))) float f32x4;
typedef __attribute__((ext_vector_type(2))) float v2f;

__device__ __forceinline__ u16 f32_to_bf16_rne(float f) {
    u32 u = __float_as_uint(f);
    u32 r = (u + 0x7FFFu + ((u >> 16) & 1u)) >> 16;
    return (u16)r;
}
__device__ __forceinline__ float bf16_lo(u32 x) { return __uint_as_float(x << 16); }
__device__ __forceinline__ u32 pack_bf16(float lo, float hi) {
    return (u32)f32_to_bf16_rne(lo) | ((u32)f32_to_bf16_rne(hi) << 16);
}
// unpack a bf16-pair dword into a packed f32 pair (feeds v_pk_fma_f32)
__device__ __forceinline__ v2f up2(u32 w) {
    v2f r;
    r.x = __uint_as_float(w << 16);
    r.y = __uint_as_float(w & 0xFFFF0000u);
    return r;
}

// ===========================================================================
// e0 -> bf16 (user ++ item) and W0/W1 -> bf16, one dispatch
// ===========================================================================
__global__ __launch_bounds__(256) void conv_all(
    const float* __restrict__ uemb, const float* __restrict__ iemb,
    const float* __restrict__ W0, const float* __restrict__ W1,
    u16* __restrict__ ebf, u16* __restrict__ Wbf0, u16* __restrict__ Wbf1)
{
    const int gid = blockIdx.x * 256 + threadIdx.x;
    const int i = gid * 4;
    if (i < N_NODES * EMB) {
        const float* src = (i < N_USERS * EMB) ? uemb + i : iemb + (i - N_USERS * EMB);
        const float4 v = *(const float4*)src;
        ushort4 w;
        w.x = f32_to_bf16_rne(v.x);
        w.y = f32_to_bf16_rne(v.y);
        w.z = f32_to_bf16_rne(v.z);
        w.w = f32_to_bf16_rne(v.w);
        *(ushort4*)(ebf + i) = w;
    }
    if (gid < EMB * EMB) {
        Wbf0[gid] = f32_to_bf16_rne(W0[gid]);
        Wbf1[gid] = f32_to_bf16_rne(W1[gid]);
    }
}

// ===========================================================================
// Per-chunk bucket histogram -> H[chunk][NBKT] (no global atomics)
// ===========================================================================
__global__ __launch_bounds__(1024) void bkt_hist(
    const int* __restrict__ rows, int* __restrict__ H)
{
    __shared__ int cnt[NBKT];
    const int t = threadIdx.x;
    const int c = blockIdx.x;
    for (int b = t; b < NBKT; b += 1024) cnt[b] = 0;
    __syncthreads();

    const int e0 = c * L1_CHUNK;
    const int e1 = (e0 + L1_CHUNK < N_EDGES) ? e0 + L1_CHUNK : N_EDGES;
    for (int i = e0 + t; i < e1; i += 1024)
        atomicAdd(&cnt[rows[i] >> RB_SHIFT], 1);
    __syncthreads();

    for (int b = t; b < NBKT; b += 1024) H[c * NBKT + b] = cnt[b];
}

// ===========================================================================
// scan_plus (single block): bucket totals -> bkt_ptr; B[c][b] bases.
// ===========================================================================
__global__ __launch_bounds__(1024) void scan_plus(
    const int* __restrict__ H, int* __restrict__ bkt_ptr,
    int* __restrict__ B)
{
    __shared__ int lds[1024];
    const int t = threadIdx.x;

    int v[SCAN_ITEMS];
    int s = 0;
    #pragma unroll
    for (int j = 0; j < SCAN_ITEMS; ++j) {
        const int idx = t * SCAN_ITEMS + j;
        int tot = 0;
        if (idx < NBKT) {
            int c = 0;
            int s0 = 0, s1 = 0, s2 = 0, s3 = 0;
            for (; c + 4 <= NCH; c += 4) {
                s0 += H[(c + 0) * NBKT + idx];
                s1 += H[(c + 1) * NBKT + idx];
                s2 += H[(c + 2) * NBKT + idx];
                s3 += H[(c + 3) * NBKT + idx];
            }
            for (; c < NCH; ++c) s0 += H[c * NBKT + idx];
            tot = (s0 + s1) + (s2 + s3);
        }
        v[j] = tot;
        s += tot;
    }
    lds[t] = s;
    __syncthreads();
    for (int off = 1; off < 1024; off <<= 1) {
        int x = 0;
        if (t >= off) x = lds[t - off];
        __syncthreads();
        lds[t] += x;
        __syncthreads();
    }
    int run = lds[t] - s;   // exclusive prefix of this thread's group

    #pragma unroll
    for (int j = 0; j < SCAN_ITEMS; ++j) {
        const int idx = t * SCAN_ITEMS + j;
        if (idx < NBKT) {
            bkt_ptr[idx] = run;
            int r2 = run;
            for (int c = 0; c < NCH; ++c) {
                B[c * NBKT + idx] = r2;
                r2 += H[c * NBKT + idx];
            }
            run += v[j];
        }
    }
    if (t == 0) bkt_ptr[NBKT] = N_EDGES;
}

// ===========================================================================
// Partition (single edge pass, no global atomics)
// record = (val, (localrow<<18)|col), localrow 7 bits
// ===========================================================================
__global__ __launch_bounds__(1024) void partition_l1(
    const float* __restrict__ vals, const int* __restrict__ rows,
    const int* __restrict__ cols, const int* __restrict__ B,
    float2* __restrict__ svc)
{
    __shared__ int base[NBKT];
    __shared__ int cnt[NBKT];
    const int t = threadIdx.x;
    const int c = blockIdx.x;
    for (int b = t; b < NBKT; b += 1024) {
        base[b] = B[c * NBKT + b];
        cnt[b]  = 0;
    }
    __syncthreads();

    const int e0 = c * L1_CHUNK;
    const int e1 = (e0 + L1_CHUNK < N_EDGES) ? e0 + L1_CHUNK : N_EDGES;
    for (int i = e0 + t; i < e1; i += 1024) {
        const int r = rows[i];
        const int b = r >> RB_SHIFT;
        const int pos = base[b] + atomicAdd(&cnt[b], 1);
        const u32 packed = ((u32)(r & (RB - 1)) << 18) | (u32)cols[i];
        svc[pos] = make_float2(vals[i], __uint_as_float(packed));
    }
}

// ===========================================================================
// place_l2: per-row count (LDS) -> LDS scan -> row_ptr -> in-bucket
// placement via LDS heads. RB=128 -> 1172 blocks (2x TLP). PLAIN stores:
// block's writes stay in a ~16KB range so one XCD L2 assembles full lines.
// ===========================================================================
__global__ __launch_bounds__(256) void place_l2(
    const int* __restrict__ bkt_ptr, const float2* __restrict__ svc,
    float2* __restrict__ sedge, int* __restrict__ row_ptr)
{
    __shared__ int cnt[RB];
    __shared__ int heads[RB];
    const int b     = blockIdx.x;
    const int rbase = b << RB_SHIFT;
    const int t     = threadIdx.x;

    if (t < RB) cnt[t] = 0;
    __syncthreads();

    const int lo = bkt_ptr[b];
    const int hi = bkt_ptr[b + 1];

    for (int i = lo + t; i < hi; i += 256)
        atomicAdd(&cnt[__float_as_uint(svc[i].y) >> 18], 1);
    __syncthreads();

    int v = 0;
    if (t < RB) v = cnt[t];
    for (int off = 1; off < RB; off <<= 1) {
        int x = 0;
        if (t < RB && t >= off) x = cnt[t - off];
        __syncthreads();
        if (t < RB) cnt[t] += x;
        __syncthreads();
    }
    if (t < RB) {
        const int excl = cnt[t] - v;
        heads[t] = lo + excl;
        const int gr = rbase + t;
        if (gr <= N_NODES) row_ptr[gr] = lo + excl;
    }
    __syncthreads();

    for (int i = lo + t; i < hi; i += 256) {
        const float2 vc = svc[i];
        const int lr  = (int)(__float_as_uint(vc.y) >> 18);
        const int pos = atomicAdd(&heads[lr], 1);
        sedge[pos] = vc;
    }
}

// ===========================================================================
// Pull-SpMM over bf16 source (round-16 proven): dwordx4 gather, single
// predicated 16-wide loop, packed v2f accumulate (v_pk_fma_f32).
// ===========================================================================
__global__ __launch_bounds__(256) void spmm_bf16(
    const int* __restrict__ row_ptr,     // N_NODES+1
    const float2* __restrict__ sedge,    // (val, packed) row-sorted
    const u16* __restrict__ ebf,         // [N_NODES][64] bf16
    u16* __restrict__ tbf)               // [N_NODES][64] bf16
{
    const int tid  = threadIdx.x;
    const int lane = tid & 63;
    const int row  = blockIdx.x * 4 + (tid >> 6);
    if (row >= N_NODES) return;

    const int g = lane >> 3;    // edge slot 0..7
    const int q = lane & 7;     // feature octet -> features 8q..8q+7

    const int beg = row_ptr[row];
    const int end = row_ptr[row + 1];

    v2f A0 = {0.f, 0.f}, A1 = {0.f, 0.f}, A2 = {0.f, 0.f}, A3 = {0.f, 0.f};

    for (int k = beg; k < end; k += 16) {
        const int  kA  = k + g;
        const int  kB  = k + 8 + g;
        const bool onA = kA < end;
        const bool onB = kB < end;
        const float2 mA = sedge[onA ? kA : end - 1];
        const float2 mB = sedge[onB ? kB : end - 1];
        const float vA = onA ? mA.x : 0.f;
        const float vB = onB ? mB.x : 0.f;
        const u32 iA = __float_as_uint(mA.y) & COL_MASK;
        const u32 iB = __float_as_uint(mB.y) & COL_MASK;
        const uint4 xA = *((const uint4*)(ebf + (size_t)iA * EMB) + q);
        const uint4 xB = *((const uint4*)(ebf + (size_t)iB * EMB) + q);
        const v2f vvA = {vA, vA};
        const v2f vvB = {vB, vB};
        A0 = vvA * up2(xA.x) + A0;
        A1 = vvA * up2(xA.y) + A1;
        A2 = vvA * up2(xA.z) + A2;
        A3 = vvA * up2(xA.w) + A3;
        A0 = vvB * up2(xB.x) + A0;
        A1 = vvB * up2(xB.y) + A1;
        A2 = vvB * up2(xB.z) + A2;
        A3 = vvB * up2(xB.w) + A3;
    }

    // reduce across the 8 edge slots (xor 8,16,32) per f32 component
    float s0 = A0.x, s1 = A0.y, s2 = A1.x, s3 = A1.y;
    float s4 = A2.x, s5 = A2.y, s6 = A3.x, s7 = A3.y;
    s0 += __shfl_xor(s0, 8); s0 += __shfl_xor(s0, 16); s0 += __shfl_xor(s0, 32);
    s1 += __shfl_xor(s1, 8); s1 += __shfl_xor(s1, 16); s1 += __shfl_xor(s1, 32);
    s2 += __shfl_xor(s2, 8); s2 += __shfl_xor(s2, 16); s2 += __shfl_xor(s2, 32);
    s3 += __shfl_xor(s3, 8); s3 += __shfl_xor(s3, 16); s3 += __shfl_xor(s3, 32);
    s4 += __shfl_xor(s4, 8); s4 += __shfl_xor(s4, 16); s4 += __shfl_xor(s4, 32);
    s5 += __shfl_xor(s5, 8); s5 += __shfl_xor(s5, 16); s5 += __shfl_xor(s5, 32);
    s6 += __shfl_xor(s6, 8); s6 += __shfl_xor(s6, 16); s6 += __shfl_xor(s6, 32);
    s7 += __shfl_xor(s7, 8); s7 += __shfl_xor(s7, 16); s7 += __shfl_xor(s7, 32);

    if (g == 0) {
        uint4 w;
        w.x = pack_bf16(s0, s1);
        w.y = pack_bf16(s2, s3);
        w.z = pack_bf16(s4, s5);
        w.w = pack_bf16(s6, s7);
        *(uint4*)(tbf + (size_t)row * EMB + 8 * q) = w;
    }
}

// ===========================================================================
// Dense stage via MFMA: e1 = t @ W^T fused with LeakyReLU + mean-accum.
// FIRST: obf = bf16(0.25*(e0+e1+e2)), e2 -> ebf.  (no f32 out traffic)
// !FIRST: out = f32(obf) + 0.25*e3   (single f32 write of d_out)
// ===========================================================================
template <bool FIRST>
__global__ __launch_bounds__(256) void dense_mfma(
    const u16* __restrict__ tbf,     // [N_NODES][64] bf16
    const u16* __restrict__ Wbf,     // [64][64] bf16
    u16* ebf,                        // FIRST: e0 read + e2 write (same elem)
    u16* __restrict__ obf,           // partial mean, bf16
    float* __restrict__ out)
{
    const int tid  = threadIdx.x;
    const int l    = tid & 63;
    const int tile = blockIdx.x * 4 + (tid >> 6);
    if (tile >= NTILE) return;
    const int row0 = tile * 16;

    const int lr = l & 15;
    const int lk = l >> 4;

    short8v bfrag[4][2];
    #pragma unroll
    for (int c = 0; c < 4; ++c)
        #pragma unroll
        for (int kh = 0; kh < 2; ++kh)
            bfrag[c][kh] = *(const short8v*)(Wbf + (size_t)(16 * c + lr) * EMB
                                             + 32 * kh + 8 * lk);

    const u16* trow = tbf + (size_t)(row0 + lr) * EMB;
    const short8v afrag0 = *(const short8v*)(trow + 8 * lk);
    const short8v afrag1 = *(const short8v*)(trow + 32 + 8 * lk);

    f32x4 acc[4];
    #pragma unroll
    for (int c = 0; c < 4; ++c) {
        f32x4 z = {0.f, 0.f, 0.f, 0.f};
        z = __builtin_amdgcn_mfma_f32_16x16x32_bf16(afrag0, bfrag[c][0], z, 0, 0, 0);
        z = __builtin_amdgcn_mfma_f32_16x16x32_bf16(afrag1, bfrag[c][1], z, 0, 0, 0);
        acc[c] = z;
    }

    #pragma unroll
    for (int c = 0; c < 4; ++c) {
        #pragma unroll
        for (int r = 0; r < 4; ++r) {
            const int row = row0 + 4 * lk + r;
            const size_t idx = (size_t)row * EMB + 16 * c + lr;
            const float e1v = acc[c][r];
            if (FIRST) {
                const float e2v = (e1v >= 0.f) ? e1v : LEAKY * e1v;
                const float e0v = bf16_lo((u32)ebf[idx]);   // e0 (bf16)
                obf[idx] = f32_to_bf16_rne(0.25f * (e0v + e1v + e2v));
                ebf[idx] = f32_to_bf16_rne(e2v);            // e2 for stage 2
            } else {
                out[idx] = bf16_lo((u32)obf[idx]) + 0.25f * e1v;
            }
        }
    }
}

// ===========================================================================
// Fallback (round-1 proven): atomic SpMM + f32 dense, if ws too small.
// ===========================================================================
__global__ __launch_bounds__(256) void spmm_atomic(
    const float* __restrict__ vals, const int* __restrict__ rows,
    const int* __restrict__ cols, const float* __restrict__ src_a,
    const float* __restrict__ src_b, float* __restrict__ dst)
{
    const int tid  = threadIdx.x;
    const int lane = tid & 63;
    const int e    = blockIdx.x * 4 + (tid >> 6);
    if (e >= N_EDGES) return;
    const float v = vals[e];
    const int   c = cols[e];
    const int   r = rows[e];
    const float* src = (src_b != nullptr && c >= N_USERS)
                           ? src_b + (size_t)(c - N_USERS) * EMB
                           : src_a + (size_t)c * EMB;
    unsafeAtomicAdd(&dst[(size_t)r * EMB + lane], v * src[lane]);
}

template <bool FIRST>
__global__ __launch_bounds__(256) void dense_f32(
    const float* __restrict__ t, const float* __restrict__ W,
    const float* __restrict__ user_emb, const float* __restrict__ item_emb,
    float* __restrict__ e2, float* __restrict__ out)
{
    __shared__ float wT[64][65];
    __shared__ float trow[16][64];

    const int tid = threadIdx.x;
    for (int k = tid; k < 64 * 64; k += 256) {
        const int i = k >> 6, j = k & 63;
        wT[j][i] = W[k];
    }
    const int row_base = blockIdx.x * 16;
    for (int k = tid; k < 16 * 64; k += 256) {
        const int r = k >> 6, j = k & 63;
        const int row = row_base + r;
        trow[r][j] = (row < N_NODES) ? t[(size_t)row * EMB + j] : 0.f;
    }
    __syncthreads();

    const int i  = tid & 63;
    const int r0 = tid >> 6;

    #pragma unroll
    for (int rr = 0; rr < 4; ++rr) {
        const int r   = r0 * 4 + rr;
        const int row = row_base + r;
        if (row >= N_NODES) continue;
        float acc = 0.f;
        #pragma unroll
        for (int j = 0; j < 64; ++j)
            acc = fmaf(trow[r][j], wT[j][i], acc);
        const size_t idx = (size_t)row * EMB + i;
        if (FIRST) {
            const float e1v = acc;
            const float e2v = (e1v >= 0.f) ? e1v : LEAKY * e1v;
            const float e0v = (row < N_USERS)
                                  ? user_emb[idx]
                                  : item_emb[(size_t)(row - N_USERS) * EMB + i];
            e2[idx]  = e2v;
            out[idx] = 0.25f * (e0v + e1v + e2v);
        } else {
            out[idx] += 0.25f * acc;
        }
    }
}

// ===========================================================================
extern "C" void kernel_launch(void* const* d_in, const int* in_sizes, int n_in,
                              void* d_out, int out_size, void* d_ws, size_t ws_size,
                              hipStream_t stream)
{
    const float* user_emb = (const float*)d_in[0];
    const float* item_emb = (const float*)d_in[1];
    const float* W0       = (const float*)d_in[2];
    const float* W1       = (const float*)d_in[3];
    const float* adj_vals = (const float*)d_in[4];
    const int*   adj_rows = (const int*)d_in[5];
    const int*   adj_cols = (const int*)d_in[6];
    float*       out      = (float*)d_out;

    const size_t mat_bytes = (size_t)N_NODES * EMB * sizeof(float);   // 38.4 MB
    const size_t ebf_bytes = (size_t)N_NODES * EMB * sizeof(u16);     // 19.2 MB
    const size_t edge8     = (size_t)N_EDGES * sizeof(float2);        // 19.2 MB
    const size_t hmat      = (size_t)NCH * NBKT * sizeof(int);        // 0.69 MB

    // layout: [tbf | svc transient] [sedge] [ebf] [obf] [aux] [Wbf]
    const size_t off_tbf    = 0;
    const size_t off_svc    = 0;                       // transient, inside tbf
    const size_t off_sedge  = off_tbf + ebf_bytes;
    const size_t off_ebf    = off_sedge + edge8;
    const size_t off_obf    = off_ebf + ebf_bytes;
    const size_t off_rowptr = off_obf + ebf_bytes;
    const size_t off_H      = off_rowptr + (size_t)(N_NODES + 1) * sizeof(int);
    const size_t off_B      = off_H + hmat;
    const size_t off_ptr    = off_B + hmat;
    const size_t off_wbf    = (off_ptr + (size_t)(NBKT + 1) * sizeof(int) + 15) & ~(size_t)15;
    const size_t required   = off_wbf + 2 * (size_t)EMB * EMB * sizeof(u16); // ~79.5 MB

    const int spmm_blocks   = (N_NODES + 3) / 4;       // 37500
    const int densem_blocks = (NTILE + 3) / 4;         // 2344
    const int conv_blocks   = (N_NODES * EMB / 4 + 255) / 256;

    if (ws_size >= required) {
        u16*    tbf     = (u16*)((char*)d_ws + off_tbf);
        float2* svc     = (float2*)((char*)d_ws + off_svc);
        float2* sedge   = (float2*)((char*)d_ws + off_sedge);
        u16*    ebf     = (u16*)((char*)d_ws + off_ebf);
        u16*    obf     = (u16*)((char*)d_ws + off_obf);
        int*    row_ptr = (int*)((char*)d_ws + off_rowptr);
        int*    H       = (int*)((char*)d_ws + off_H);
        int*    B       = (int*)((char*)d_ws + off_B);
        int*    bkt_ptr = (int*)((char*)d_ws + off_ptr);
        u16*    Wbf0    = (u16*)((char*)d_ws + off_wbf);
        u16*    Wbf1    = Wbf0 + EMB * EMB;

        // ---- bf16 sources (e0, W0, W1) ----
        conv_all<<<conv_blocks, 256, 0, stream>>>(
            user_emb, item_emb, W0, W1, ebf, Wbf0, Wbf1);

        // ---- bucket-sorted edge list + row_ptr (once, reused twice) ----
        bkt_hist<<<NCH, 1024, 0, stream>>>(adj_rows, H);
        scan_plus<<<1, 1024, 0, stream>>>(H, bkt_ptr, B);
        partition_l1<<<NCH, 1024, 0, stream>>>(
            adj_vals, adj_rows, adj_cols, B, svc);
        place_l2<<<NBKT, 256, 0, stream>>>(bkt_ptr, svc, sedge, row_ptr);
        // svc (inside tbf) is dead from here on

        // ---- stage 1: tbf = A @ e0 ; obf = 0.25(e0+e1+e2) ; e2 -> ebf ----
        spmm_bf16<<<spmm_blocks, 256, 0, stream>>>(row_ptr, sedge, ebf, tbf);
        dense_mfma<true><<<densem_blocks, 256, 0, stream>>>(
            tbf, Wbf0, ebf, obf, out);

        // ---- stage 2: tbf = A @ e2 ; out = obf + 0.25*e3 ----
        spmm_bf16<<<spmm_blocks, 256, 0, stream>>>(row_ptr, sedge, ebf, tbf);
        dense_mfma<false><<<densem_blocks, 256, 0, stream>>>(
            tbf, Wbf1, ebf, obf, out);
    } else {
        // ---- fallback: round-1 atomic path ----
        float* t  = (float*)d_ws;
        float* e2 = (float*)((char*)d_ws + mat_bytes);
        const int dense_blocks = (N_NODES + 15) / 16;

        hipMemsetAsync(t, 0, mat_bytes, stream);
        spmm_atomic<<<(N_EDGES + 3) / 4, 256, 0, stream>>>(
            adj_vals, adj_rows, adj_cols, user_emb, item_emb, t);
        dense_f32<true><<<dense_blocks, 256, 0, stream>>>(
            t, W0, user_emb, item_emb, e2, out);

        hipMemsetAsync(t, 0, mat_bytes, stream);
        spmm_atomic<<<(N_EDGES + 3) / 4, 256, 0, stream>>>(
            adj_vals, adj_rows, adj_cols, e2, nullptr, t);
        dense_f32<false><<<dense_blocks, 256, 0, stream>>>(
            t, W1, nullptr, nullptr, nullptr, out);
    }
}

// Round 19
// 243.870 us; speedup vs baseline: 1.1375x; 1.1290x over previous
//
#include <hip/hip_runtime.h>

#define N_USERS 100000
#define N_ITEMS 50000
#define N_NODES 150000
#define N_EDGES 2400000
#define EMB 64
#define LEAKY 0.3f

#define RB_SHIFT 7                                         // 128 rows / bucket
#define RB (1 << RB_SHIFT)
#define NBKT ((N_NODES + RB - 1) >> RB_SHIFT)              // 1172
#define L1_CHUNK 16384
#define NCH ((N_EDGES + L1_CHUNK - 1) / L1_CHUNK)          // 147 chunks
#define SCAN_ITEMS ((NBKT + 1023) / 1024)                  // 2
#define COL_MASK 0x3FFFFu                                  // col < 2^18
#define NTILE (N_NODES / 16)                               // 9375 (exact)

typedef unsigned short u16;
typedef unsigned int   u32;
typedef __attribute__((ext_vector_type(8))) short short8v;
typedef __attribute__((ext_vector_type(4))) float f32x4;
typedef __attribute__((ext_vector_type(2))) float v2f;

__device__ __forceinline__ u16 f32_to_bf16_rne(float f) {
    u32 u = __float_as_uint(f);
    u32 r = (u + 0x7FFFu + ((u >> 16) & 1u)) >> 16;
    return (u16)r;
}
__device__ __forceinline__ float bf16_lo(u32 x) { return __uint_as_float(x << 16); }
__device__ __forceinline__ u32 pack_bf16(float lo, float hi) {
    return (u32)f32_to_bf16_rne(lo) | ((u32)f32_to_bf16_rne(hi) << 16);
}
// unpack a bf16-pair dword into a packed f32 pair (feeds v_pk_fma_f32)
__device__ __forceinline__ v2f up2(u32 w) {
    v2f r;
    r.x = __uint_as_float(w << 16);
    r.y = __uint_as_float(w & 0xFFFF0000u);
    return r;
}

// ===========================================================================
// e0 -> bf16 (user ++ item) and W0/W1 -> bf16, one dispatch
// ===========================================================================
__global__ __launch_bounds__(256) void conv_all(
    const float* __restrict__ uemb, const float* __restrict__ iemb,
    const float* __restrict__ W0, const float* __restrict__ W1,
    u16* __restrict__ ebf, u16* __restrict__ Wbf0, u16* __restrict__ Wbf1)
{
    const int gid = blockIdx.x * 256 + threadIdx.x;
    const int i = gid * 4;
    if (i < N_NODES * EMB) {
        const float* src = (i < N_USERS * EMB) ? uemb + i : iemb + (i - N_USERS * EMB);
        const float4 v = *(const float4*)src;
        ushort4 w;
        w.x = f32_to_bf16_rne(v.x);
        w.y = f32_to_bf16_rne(v.y);
        w.z = f32_to_bf16_rne(v.z);
        w.w = f32_to_bf16_rne(v.w);
        *(ushort4*)(ebf + i) = w;
    }
    if (gid < EMB * EMB) {
        Wbf0[gid] = f32_to_bf16_rne(W0[gid]);
        Wbf1[gid] = f32_to_bf16_rne(W1[gid]);
    }
}

// ===========================================================================
// Per-chunk bucket histogram -> H[chunk][NBKT] (no global atomics)
// ===========================================================================
__global__ __launch_bounds__(1024) void bkt_hist(
    const int* __restrict__ rows, int* __restrict__ H)
{
    __shared__ int cnt[NBKT];
    const int t = threadIdx.x;
    const int c = blockIdx.x;
    for (int b = t; b < NBKT; b += 1024) cnt[b] = 0;
    __syncthreads();

    const int e0 = c * L1_CHUNK;
    const int e1 = (e0 + L1_CHUNK < N_EDGES) ? e0 + L1_CHUNK : N_EDGES;
    for (int i = e0 + t; i < e1; i += 1024)
        atomicAdd(&cnt[rows[i] >> RB_SHIFT], 1);
    __syncthreads();

    for (int b = t; b < NBKT; b += 1024) H[c * NBKT + b] = cnt[b];
}

// ===========================================================================
// scan_bkt (single block, 1024 thr): bucket totals (8 loads in flight:
// 4-chunk unroll x 2 buckets) -> LDS exclusive scan -> bkt_ptr.
// ===========================================================================
__global__ __launch_bounds__(1024) void scan_bkt(
    const int* __restrict__ H, int* __restrict__ bkt_ptr)
{
    __shared__ int lds[1024];
    const int t = threadIdx.x;
    const int i0 = t * SCAN_ITEMS;          // bucket for j=0
    const int i1 = t * SCAN_ITEMS + 1;      // bucket for j=1
    const bool on0 = i0 < NBKT;
    const bool on1 = i1 < NBKT;

    int t0 = 0, t1 = 0;
    {
        int a0 = 0, a1 = 0, a2 = 0, a3 = 0;
        int b0 = 0, b1 = 0, b2 = 0, b3 = 0;
        int c = 0;
        for (; c + 4 <= NCH; c += 4) {      // 8 independent loads / iter
            if (on0) {
                a0 += H[(c + 0) * NBKT + i0];
                a1 += H[(c + 1) * NBKT + i0];
                a2 += H[(c + 2) * NBKT + i0];
                a3 += H[(c + 3) * NBKT + i0];
            }
            if (on1) {
                b0 += H[(c + 0) * NBKT + i1];
                b1 += H[(c + 1) * NBKT + i1];
                b2 += H[(c + 2) * NBKT + i1];
                b3 += H[(c + 3) * NBKT + i1];
            }
        }
        for (; c < NCH; ++c) {
            if (on0) a0 += H[c * NBKT + i0];
            if (on1) b0 += H[c * NBKT + i1];
        }
        t0 = (a0 + a1) + (a2 + a3);
        t1 = (b0 + b1) + (b2 + b3);
    }

    const int s = t0 + t1;
    lds[t] = s;
    __syncthreads();
    for (int off = 1; off < 1024; off <<= 1) {
        int x = 0;
        if (t >= off) x = lds[t - off];
        __syncthreads();
        lds[t] += x;
        __syncthreads();
    }
    int run = lds[t] - s;   // exclusive prefix of this thread's pair
    if (on0) bkt_ptr[i0] = run;
    if (on1) bkt_ptr[i1] = run + t0;
    if (t == 0) bkt_ptr[NBKT] = N_EDGES;
}

// ===========================================================================
// fill_B (parallel over buckets): one thread per bucket, 4-unrolled
// running prefix along chunks. B[c][b] = bkt_ptr[b] + prefix_c(H[.][b]).
// ===========================================================================
__global__ __launch_bounds__(256) void fill_B(
    const int* __restrict__ H, const int* __restrict__ bkt_ptr,
    int* __restrict__ B)
{
    const int b = blockIdx.x * 256 + threadIdx.x;
    if (b >= NBKT) return;
    int run = bkt_ptr[b];
    int c = 0;
    for (; c + 4 <= NCH; c += 4) {           // 4 loads in flight
        const int h0 = H[(c + 0) * NBKT + b];
        const int h1 = H[(c + 1) * NBKT + b];
        const int h2 = H[(c + 2) * NBKT + b];
        const int h3 = H[(c + 3) * NBKT + b];
        B[(c + 0) * NBKT + b] = run;
        B[(c + 1) * NBKT + b] = run + h0;
        B[(c + 2) * NBKT + b] = run + h0 + h1;
        B[(c + 3) * NBKT + b] = run + h0 + h1 + h2;
        run += h0 + h1 + h2 + h3;
    }
    for (; c < NCH; ++c) {
        B[c * NBKT + b] = run;
        run += H[c * NBKT + b];
    }
}

// ===========================================================================
// Partition (single edge pass, no global atomics)
// record = (val, (localrow<<18)|col), localrow 7 bits
// ===========================================================================
__global__ __launch_bounds__(1024) void partition_l1(
    const float* __restrict__ vals, const int* __restrict__ rows,
    const int* __restrict__ cols, const int* __restrict__ B,
    float2* __restrict__ svc)
{
    __shared__ int base[NBKT];
    __shared__ int cnt[NBKT];
    const int t = threadIdx.x;
    const int c = blockIdx.x;
    for (int b = t; b < NBKT; b += 1024) {
        base[b] = B[c * NBKT + b];
        cnt[b]  = 0;
    }
    __syncthreads();

    const int e0 = c * L1_CHUNK;
    const int e1 = (e0 + L1_CHUNK < N_EDGES) ? e0 + L1_CHUNK : N_EDGES;
    for (int i = e0 + t; i < e1; i += 1024) {
        const int r = rows[i];
        const int b = r >> RB_SHIFT;
        const int pos = base[b] + atomicAdd(&cnt[b], 1);
        const u32 packed = ((u32)(r & (RB - 1)) << 18) | (u32)cols[i];
        svc[pos] = make_float2(vals[i], __uint_as_float(packed));
    }
}

// ===========================================================================
// place_l2: per-row count (LDS) -> LDS scan -> row_ptr -> in-bucket
// placement via LDS heads. RB=128 -> 1172 blocks (2x TLP). PLAIN stores:
// block's writes stay in a ~16KB range so one XCD L2 assembles full lines.
// ===========================================================================
__global__ __launch_bounds__(256) void place_l2(
    const int* __restrict__ bkt_ptr, const float2* __restrict__ svc,
    float2* __restrict__ sedge, int* __restrict__ row_ptr)
{
    __shared__ int cnt[RB];
    __shared__ int heads[RB];
    const int b     = blockIdx.x;
    const int rbase = b << RB_SHIFT;
    const int t     = threadIdx.x;

    if (t < RB) cnt[t] = 0;
    __syncthreads();

    const int lo = bkt_ptr[b];
    const int hi = bkt_ptr[b + 1];

    for (int i = lo + t; i < hi; i += 256)
        atomicAdd(&cnt[__float_as_uint(svc[i].y) >> 18], 1);
    __syncthreads();

    int v = 0;
    if (t < RB) v = cnt[t];
    for (int off = 1; off < RB; off <<= 1) {
        int x = 0;
        if (t < RB && t >= off) x = cnt[t - off];
        __syncthreads();
        if (t < RB) cnt[t] += x;
        __syncthreads();
    }
    if (t < RB) {
        const int excl = cnt[t] - v;
        heads[t] = lo + excl;
        const int gr = rbase + t;
        if (gr <= N_NODES) row_ptr[gr] = lo + excl;
    }
    __syncthreads();

    for (int i = lo + t; i < hi; i += 256) {
        const float2 vc = svc[i];
        const int lr  = (int)(__float_as_uint(vc.y) >> 18);
        const int pos = atomicAdd(&heads[lr], 1);
        sedge[pos] = vc;
    }
}

// ===========================================================================
// Pull-SpMM over bf16 source (round-16 proven): dwordx4 gather, single
// predicated 16-wide loop, packed v2f accumulate (v_pk_fma_f32).
// ===========================================================================
__global__ __launch_bounds__(256) void spmm_bf16(
    const int* __restrict__ row_ptr,     // N_NODES+1
    const float2* __restrict__ sedge,    // (val, packed) row-sorted
    const u16* __restrict__ ebf,         // [N_NODES][64] bf16
    u16* __restrict__ tbf)               // [N_NODES][64] bf16
{
    const int tid  = threadIdx.x;
    const int lane = tid & 63;
    const int row  = blockIdx.x * 4 + (tid >> 6);
    if (row >= N_NODES) return;

    const int g = lane >> 3;    // edge slot 0..7
    const int q = lane & 7;     // feature octet -> features 8q..8q+7

    const int beg = row_ptr[row];
    const int end = row_ptr[row + 1];

    v2f A0 = {0.f, 0.f}, A1 = {0.f, 0.f}, A2 = {0.f, 0.f}, A3 = {0.f, 0.f};

    for (int k = beg; k < end; k += 16) {
        const int  kA  = k + g;
        const int  kB  = k + 8 + g;
        const bool onA = kA < end;
        const bool onB = kB < end;
        const float2 mA = sedge[onA ? kA : end - 1];
        const float2 mB = sedge[onB ? kB : end - 1];
        const float vA = onA ? mA.x : 0.f;
        const float vB = onB ? mB.x : 0.f;
        const u32 iA = __float_as_uint(mA.y) & COL_MASK;
        const u32 iB = __float_as_uint(mB.y) & COL_MASK;
        const uint4 xA = *((const uint4*)(ebf + (size_t)iA * EMB) + q);
        const uint4 xB = *((const uint4*)(ebf + (size_t)iB * EMB) + q);
        const v2f vvA = {vA, vA};
        const v2f vvB = {vB, vB};
        A0 = vvA * up2(xA.x) + A0;
        A1 = vvA * up2(xA.y) + A1;
        A2 = vvA * up2(xA.z) + A2;
        A3 = vvA * up2(xA.w) + A3;
        A0 = vvB * up2(xB.x) + A0;
        A1 = vvB * up2(xB.y) + A1;
        A2 = vvB * up2(xB.z) + A2;
        A3 = vvB * up2(xB.w) + A3;
    }

    // reduce across the 8 edge slots (xor 8,16,32) per f32 component
    float s0 = A0.x, s1 = A0.y, s2 = A1.x, s3 = A1.y;
    float s4 = A2.x, s5 = A2.y, s6 = A3.x, s7 = A3.y;
    s0 += __shfl_xor(s0, 8); s0 += __shfl_xor(s0, 16); s0 += __shfl_xor(s0, 32);
    s1 += __shfl_xor(s1, 8); s1 += __shfl_xor(s1, 16); s1 += __shfl_xor(s1, 32);
    s2 += __shfl_xor(s2, 8); s2 += __shfl_xor(s2, 16); s2 += __shfl_xor(s2, 32);
    s3 += __shfl_xor(s3, 8); s3 += __shfl_xor(s3, 16); s3 += __shfl_xor(s3, 32);
    s4 += __shfl_xor(s4, 8); s4 += __shfl_xor(s4, 16); s4 += __shfl_xor(s4, 32);
    s5 += __shfl_xor(s5, 8); s5 += __shfl_xor(s5, 16); s5 += __shfl_xor(s5, 32);
    s6 += __shfl_xor(s6, 8); s6 += __shfl_xor(s6, 16); s6 += __shfl_xor(s6, 32);
    s7 += __shfl_xor(s7, 8); s7 += __shfl_xor(s7, 16); s7 += __shfl_xor(s7, 32);

    if (g == 0) {
        uint4 w;
        w.x = pack_bf16(s0, s1);
        w.y = pack_bf16(s2, s3);
        w.z = pack_bf16(s4, s5);
        w.w = pack_bf16(s6, s7);
        *(uint4*)(tbf + (size_t)row * EMB + 8 * q) = w;
    }
}

// ===========================================================================
// Dense stage via MFMA: e1 = t @ W^T fused with LeakyReLU + mean-accum.
// FIRST: obf = bf16(0.25*(e0+e1+e2)), e2 -> ebf.  (no f32 out traffic)
// !FIRST: out = f32(obf) + 0.25*e3   (single f32 write of d_out)
// ===========================================================================
template <bool FIRST>
__global__ __launch_bounds__(256) void dense_mfma(
    const u16* __restrict__ tbf,     // [N_NODES][64] bf16
    const u16* __restrict__ Wbf,     // [64][64] bf16
    u16* ebf,                        // FIRST: e0 read + e2 write (same elem)
    u16* __restrict__ obf,           // partial mean, bf16
    float* __restrict__ out)
{
    const int tid  = threadIdx.x;
    const int l    = tid & 63;
    const int tile = blockIdx.x * 4 + (tid >> 6);
    if (tile >= NTILE) return;
    const int row0 = tile * 16;

    const int lr = l & 15;
    const int lk = l >> 4;

    short8v bfrag[4][2];
    #pragma unroll
    for (int c = 0; c < 4; ++c)
        #pragma unroll
        for (int kh = 0; kh < 2; ++kh)
            bfrag[c][kh] = *(const short8v*)(Wbf + (size_t)(16 * c + lr) * EMB
                                             + 32 * kh + 8 * lk);

    const u16* trow = tbf + (size_t)(row0 + lr) * EMB;
    const short8v afrag0 = *(const short8v*)(trow + 8 * lk);
    const short8v afrag1 = *(const short8v*)(trow + 32 + 8 * lk);

    f32x4 acc[4];
    #pragma unroll
    for (int c = 0; c < 4; ++c) {
        f32x4 z = {0.f, 0.f, 0.f, 0.f};
        z = __builtin_amdgcn_mfma_f32_16x16x32_bf16(afrag0, bfrag[c][0], z, 0, 0, 0);
        z = __builtin_amdgcn_mfma_f32_16x16x32_bf16(afrag1, bfrag[c][1], z, 0, 0, 0);
        acc[c] = z;
    }

    #pragma unroll
    for (int c = 0; c < 4; ++c) {
        #pragma unroll
        for (int r = 0; r < 4; ++r) {
            const int row = row0 + 4 * lk + r;
            const size_t idx = (size_t)row * EMB + 16 * c + lr;
            const float e1v = acc[c][r];
            if (FIRST) {
                const float e2v = (e1v >= 0.f) ? e1v : LEAKY * e1v;
                const float e0v = bf16_lo((u32)ebf[idx]);   // e0 (bf16)
                obf[idx] = f32_to_bf16_rne(0.25f * (e0v + e1v + e2v));
                ebf[idx] = f32_to_bf16_rne(e2v);            // e2 for stage 2
            } else {
                out[idx] = bf16_lo((u32)obf[idx]) + 0.25f * e1v;
            }
        }
    }
}

// ===========================================================================
// Fallback (round-1 proven): atomic SpMM + f32 dense, if ws too small.
// ===========================================================================
__global__ __launch_bounds__(256) void spmm_atomic(
    const float* __restrict__ vals, const int* __restrict__ rows,
    const int* __restrict__ cols, const float* __restrict__ src_a,
    const float* __restrict__ src_b, float* __restrict__ dst)
{
    const int tid  = threadIdx.x;
    const int lane = tid & 63;
    const int e    = blockIdx.x * 4 + (tid >> 6);
    if (e >= N_EDGES) return;
    const float v = vals[e];
    const int   c = cols[e];
    const int   r = rows[e];
    const float* src = (src_b != nullptr && c >= N_USERS)
                           ? src_b + (size_t)(c - N_USERS) * EMB
                           : src_a + (size_t)c * EMB;
    unsafeAtomicAdd(&dst[(size_t)r * EMB + lane], v * src[lane]);
}

template <bool FIRST>
__global__ __launch_bounds__(256) void dense_f32(
    const float* __restrict__ t, const float* __restrict__ W,
    const float* __restrict__ user_emb, const float* __restrict__ item_emb,
    float* __restrict__ e2, float* __restrict__ out)
{
    __shared__ float wT[64][65];
    __shared__ float trow[16][64];

    const int tid = threadIdx.x;
    for (int k = tid; k < 64 * 64; k += 256) {
        const int i = k >> 6, j = k & 63;
        wT[j][i] = W[k];
    }
    const int row_base = blockIdx.x * 16;
    for (int k = tid; k < 16 * 64; k += 256) {
        const int r = k >> 6, j = k & 63;
        const int row = row_base + r;
        trow[r][j] = (row < N_NODES) ? t[(size_t)row * EMB + j] : 0.f;
    }
    __syncthreads();

    const int i  = tid & 63;
    const int r0 = tid >> 6;

    #pragma unroll
    for (int rr = 0; rr < 4; ++rr) {
        const int r   = r0 * 4 + rr;
        const int row = row_base + r;
        if (row >= N_NODES) continue;
        float acc = 0.f;
        #pragma unroll
        for (int j = 0; j < 64; ++j)
            acc = fmaf(trow[r][j], wT[j][i], acc);
        const size_t idx = (size_t)row * EMB + i;
        if (FIRST) {
            const float e1v = acc;
            const float e2v = (e1v >= 0.f) ? e1v : LEAKY * e1v;
            const float e0v = (row < N_USERS)
                                  ? user_emb[idx]
                                  : item_emb[(size_t)(row - N_USERS) * EMB + i];
            e2[idx]  = e2v;
            out[idx] = 0.25f * (e0v + e1v + e2v);
        } else {
            out[idx] += 0.25f * acc;
        }
    }
}

// ===========================================================================
extern "C" void kernel_launch(void* const* d_in, const int* in_sizes, int n_in,
                              void* d_out, int out_size, void* d_ws, size_t ws_size,
                              hipStream_t stream)
{
    const float* user_emb = (const float*)d_in[0];
    const float* item_emb = (const float*)d_in[1];
    const float* W0       = (const float*)d_in[2];
    const float* W1       = (const float*)d_in[3];
    const float* adj_vals = (const float*)d_in[4];
    const int*   adj_rows = (const int*)d_in[5];
    const int*   adj_cols = (const int*)d_in[6];
    float*       out      = (float*)d_out;

    const size_t mat_bytes = (size_t)N_NODES * EMB * sizeof(float);   // 38.4 MB
    const size_t ebf_bytes = (size_t)N_NODES * EMB * sizeof(u16);     // 19.2 MB
    const size_t edge8     = (size_t)N_EDGES * sizeof(float2);        // 19.2 MB
    const size_t hmat      = (size_t)NCH * NBKT * sizeof(int);        // 0.69 MB

    // layout: [tbf | svc transient] [sedge] [ebf] [obf] [aux] [Wbf]
    const size_t off_tbf    = 0;
    const size_t off_svc    = 0;                       // transient, inside tbf
    const size_t off_sedge  = off_tbf + ebf_bytes;
    const size_t off_ebf    = off_sedge + edge8;
    const size_t off_obf    = off_ebf + ebf_bytes;
    const size_t off_rowptr = off_obf + ebf_bytes;
    const size_t off_H      = off_rowptr + (size_t)(N_NODES + 1) * sizeof(int);
    const size_t off_B      = off_H + hmat;
    const size_t off_ptr    = off_B + hmat;
    const size_t off_wbf    = (off_ptr + (size_t)(NBKT + 1) * sizeof(int) + 15) & ~(size_t)15;
    const size_t required   = off_wbf + 2 * (size_t)EMB * EMB * sizeof(u16); // ~79.5 MB

    const int spmm_blocks   = (N_NODES + 3) / 4;       // 37500
    const int densem_blocks = (NTILE + 3) / 4;         // 2344
    const int conv_blocks   = (N_NODES * EMB / 4 + 255) / 256;

    if (ws_size >= required) {
        u16*    tbf     = (u16*)((char*)d_ws + off_tbf);
        float2* svc     = (float2*)((char*)d_ws + off_svc);
        float2* sedge   = (float2*)((char*)d_ws + off_sedge);
        u16*    ebf     = (u16*)((char*)d_ws + off_ebf);
        u16*    obf     = (u16*)((char*)d_ws + off_obf);
        int*    row_ptr = (int*)((char*)d_ws + off_rowptr);
        int*    H       = (int*)((char*)d_ws + off_H);
        int*    B       = (int*)((char*)d_ws + off_B);
        int*    bkt_ptr = (int*)((char*)d_ws + off_ptr);
        u16*    Wbf0    = (u16*)((char*)d_ws + off_wbf);
        u16*    Wbf1    = Wbf0 + EMB * EMB;

        // ---- bf16 sources (e0, W0, W1) ----
        conv_all<<<conv_blocks, 256, 0, stream>>>(
            user_emb, item_emb, W0, W1, ebf, Wbf0, Wbf1);

        // ---- bucket-sorted edge list + row_ptr (once, reused twice) ----
        bkt_hist<<<NCH, 1024, 0, stream>>>(adj_rows, H);
        scan_bkt<<<1, 1024, 0, stream>>>(H, bkt_ptr);
        fill_B<<<(NBKT + 255) / 256, 256, 0, stream>>>(H, bkt_ptr, B);
        partition_l1<<<NCH, 1024, 0, stream>>>(
            adj_vals, adj_rows, adj_cols, B, svc);
        place_l2<<<NBKT, 256, 0, stream>>>(bkt_ptr, svc, sedge, row_ptr);
        // svc (inside tbf) is dead from here on

        // ---- stage 1: tbf = A @ e0 ; obf = 0.25(e0+e1+e2) ; e2 -> ebf ----
        spmm_bf16<<<spmm_blocks, 256, 0, stream>>>(row_ptr, sedge, ebf, tbf);
        dense_mfma<true><<<densem_blocks, 256, 0, stream>>>(
            tbf, Wbf0, ebf, obf, out);

        // ---- stage 2: tbf = A @ e2 ; out = obf + 0.25*e3 ----
        spmm_bf16<<<spmm_blocks, 256, 0, stream>>>(row_ptr, sedge, ebf, tbf);
        dense_mfma<false><<<densem_blocks, 256, 0, stream>>>(
            tbf, Wbf1, ebf, obf, out);
    } else {
        // ---- fallback: round-1 atomic path ----
        float* t  = (float*)d_ws;
        float* e2 = (float*)((char*)d_ws + mat_bytes);
        const int dense_blocks = (N_NODES + 15) / 16;

        hipMemsetAsync(t, 0, mat_bytes, stream);
        spmm_atomic<<<(N_EDGES + 3) / 4, 256, 0, stream>>>(
            adj_vals, adj_rows, adj_cols, user_emb, item_emb, t);
        dense_f32<true><<<dense_blocks, 256, 0, stream>>>(
            t, W0, user_emb, item_emb, e2, out);

        hipMemsetAsync(t, 0, mat_bytes, stream);
        spmm_atomic<<<(N_EDGES + 3) / 4, 256, 0, stream>>>(
            adj_vals, adj_rows, adj_cols, e2, nullptr, t);
        dense_f32<false><<<dense_blocks, 256, 0, stream>>>(
            t, W1, nullptr, nullptr, nullptr, out);
    }
}

// Round 20
// 222.229 us; speedup vs baseline: 1.2483x; 1.0974x over previous
//
#include <hip/hip_runtime.h>

#define N_USERS 100000
#define N_ITEMS 50000
#define N_NODES 150000
#define N_EDGES 2400000
#define EMB 64
#define LEAKY 0.3f

#define RB_SHIFT 8                                         // 256 rows / bucket
#define RB (1 << RB_SHIFT)
#define NBKT ((N_NODES + RB - 1) >> RB_SHIFT)              // 586
#define L1_CHUNK 16384
#define NCH ((N_EDGES + L1_CHUNK - 1) / L1_CHUNK)          // 147 chunks
#define COL_MASK 0x3FFFFu                                  // col < 2^18
#define NTILE (N_NODES / 16)                               // 9375 (exact)

typedef unsigned short u16;
typedef unsigned int   u32;
typedef __attribute__((ext_vector_type(8))) short short8v;
typedef __attribute__((ext_vector_type(4))) float f32x4;
typedef __attribute__((ext_vector_type(2))) float v2f;

__device__ __forceinline__ u16 f32_to_bf16_rne(float f) {
    u32 u = __float_as_uint(f);
    u32 r = (u + 0x7FFFu + ((u >> 16) & 1u)) >> 16;
    return (u16)r;
}
__device__ __forceinline__ float bf16_lo(u32 x) { return __uint_as_float(x << 16); }
__device__ __forceinline__ u32 pack_bf16(float lo, float hi) {
    return (u32)f32_to_bf16_rne(lo) | ((u32)f32_to_bf16_rne(hi) << 16);
}
// unpack a bf16-pair dword into a packed f32 pair (feeds v_pk_fma_f32)
__device__ __forceinline__ v2f up2(u32 w) {
    v2f r;
    r.x = __uint_as_float(w << 16);
    r.y = __uint_as_float(w & 0xFFFF0000u);
    return r;
}

// ===========================================================================
// e0 -> bf16 (user ++ item) and W0/W1 -> bf16, one dispatch
// ===========================================================================
__global__ __launch_bounds__(256) void conv_all(
    const float* __restrict__ uemb, const float* __restrict__ iemb,
    const float* __restrict__ W0, const float* __restrict__ W1,
    u16* __restrict__ ebf, u16* __restrict__ Wbf0, u16* __restrict__ Wbf1)
{
    const int gid = blockIdx.x * 256 + threadIdx.x;
    const int i = gid * 4;
    if (i < N_NODES * EMB) {
        const float* src = (i < N_USERS * EMB) ? uemb + i : iemb + (i - N_USERS * EMB);
        const float4 v = *(const float4*)src;
        ushort4 w;
        w.x = f32_to_bf16_rne(v.x);
        w.y = f32_to_bf16_rne(v.y);
        w.z = f32_to_bf16_rne(v.z);
        w.w = f32_to_bf16_rne(v.w);
        *(ushort4*)(ebf + i) = w;
    }
    if (gid < EMB * EMB) {
        Wbf0[gid] = f32_to_bf16_rne(W0[gid]);
        Wbf1[gid] = f32_to_bf16_rne(W1[gid]);
    }
}

// ===========================================================================
// Per-chunk bucket histogram -> H[chunk][NBKT] (no global atomics)
// ===========================================================================
__global__ __launch_bounds__(1024) void bkt_hist(
    const int* __restrict__ rows, int* __restrict__ H)
{
    __shared__ int cnt[NBKT];
    const int t = threadIdx.x;
    const int c = blockIdx.x;
    if (t < NBKT) cnt[t] = 0;
    __syncthreads();

    const int e0 = c * L1_CHUNK;
    const int e1 = (e0 + L1_CHUNK < N_EDGES) ? e0 + L1_CHUNK : N_EDGES;
    for (int i = e0 + t; i < e1; i += 1024)
        atomicAdd(&cnt[rows[i] >> RB_SHIFT], 1);
    __syncthreads();

    if (t < NBKT) H[c * NBKT + t] = cnt[t];
}

// ===========================================================================
// scan_bkt (single block, 1024 thr): per-bucket totals (one thread per
// bucket, 4-chunk unroll) -> LDS exclusive scan -> bkt_ptr.
// ===========================================================================
__global__ __launch_bounds__(1024) void scan_bkt(
    const int* __restrict__ H, int* __restrict__ bkt_ptr)
{
    __shared__ int lds[1024];
    const int t = threadIdx.x;

    int tot = 0;
    if (t < NBKT) {
        int a0 = 0, a1 = 0, a2 = 0, a3 = 0;
        int c = 0;
        for (; c + 4 <= NCH; c += 4) {      // 4 independent loads / iter
            a0 += H[(c + 0) * NBKT + t];
            a1 += H[(c + 1) * NBKT + t];
            a2 += H[(c + 2) * NBKT + t];
            a3 += H[(c + 3) * NBKT + t];
        }
        for (; c < NCH; ++c) a0 += H[c * NBKT + t];
        tot = (a0 + a1) + (a2 + a3);
    }
    lds[t] = (t < NBKT) ? tot : 0;
    __syncthreads();
    for (int off = 1; off < 1024; off <<= 1) {
        int x = 0;
        if (t >= off) x = lds[t - off];
        __syncthreads();
        lds[t] += x;
        __syncthreads();
    }
    if (t < NBKT) bkt_ptr[t] = lds[t] - tot;
    if (t == 0) bkt_ptr[NBKT] = N_EDGES;
}

// ===========================================================================
// fill_B (parallel over buckets): one thread per bucket, 4-unrolled
// running prefix along chunks. B[c][b] = bkt_ptr[b] + prefix_c(H[.][b]).
// ===========================================================================
__global__ __launch_bounds__(256) void fill_B(
    const int* __restrict__ H, const int* __restrict__ bkt_ptr,
    int* __restrict__ B)
{
    const int b = blockIdx.x * 256 + threadIdx.x;
    if (b >= NBKT) return;
    int run = bkt_ptr[b];
    int c = 0;
    for (; c + 4 <= NCH; c += 4) {           // 4 loads in flight
        const int h0 = H[(c + 0) * NBKT + b];
        const int h1 = H[(c + 1) * NBKT + b];
        const int h2 = H[(c + 2) * NBKT + b];
        const int h3 = H[(c + 3) * NBKT + b];
        B[(c + 0) * NBKT + b] = run;
        B[(c + 1) * NBKT + b] = run + h0;
        B[(c + 2) * NBKT + b] = run + h0 + h1;
        B[(c + 3) * NBKT + b] = run + h0 + h1 + h2;
        run += h0 + h1 + h2 + h3;
    }
    for (; c < NCH; ++c) {
        B[c * NBKT + b] = run;
        run += H[c * NBKT + b];
    }
}

// ===========================================================================
// Partition (single edge pass, no global atomics)
// record = (val, (localrow<<18)|col), localrow 8 bits
// ===========================================================================
__global__ __launch_bounds__(1024) void partition_l1(
    const float* __restrict__ vals, const int* __restrict__ rows,
    const int* __restrict__ cols, const int* __restrict__ B,
    float2* __restrict__ svc)
{
    __shared__ int base[NBKT];
    __shared__ int cnt[NBKT];
    const int t = threadIdx.x;
    const int c = blockIdx.x;
    if (t < NBKT) {
        base[t] = B[c * NBKT + t];
        cnt[t]  = 0;
    }
    __syncthreads();

    const int e0 = c * L1_CHUNK;
    const int e1 = (e0 + L1_CHUNK < N_EDGES) ? e0 + L1_CHUNK : N_EDGES;
    for (int i = e0 + t; i < e1; i += 1024) {
        const int r = rows[i];
        const int b = r >> RB_SHIFT;
        const int pos = base[b] + atomicAdd(&cnt[b], 1);
        const u32 packed = ((u32)(r & (RB - 1)) << 18) | (u32)cols[i];
        svc[pos] = make_float2(vals[i], __uint_as_float(packed));
    }
}

// ===========================================================================
// place_l2: per-row count (LDS) -> LDS scan (256 counters, t<256) ->
// row_ptr -> in-bucket placement via LDS heads. 512 threads/block for TLP
// on the two edge passes; writes stay in a ~32KB range (L2 line assembly).
// ===========================================================================
__global__ __launch_bounds__(512) void place_l2(
    const int* __restrict__ bkt_ptr, const float2* __restrict__ svc,
    float2* __restrict__ sedge, int* __restrict__ row_ptr)
{
    __shared__ int cnt[RB];
    __shared__ int heads[RB];
    const int b     = blockIdx.x;
    const int rbase = b << RB_SHIFT;
    const int t     = threadIdx.x;

    if (t < RB) cnt[t] = 0;
    __syncthreads();

    const int lo = bkt_ptr[b];
    const int hi = bkt_ptr[b + 1];

    for (int i = lo + t; i < hi; i += 512)
        atomicAdd(&cnt[__float_as_uint(svc[i].y) >> 18], 1);
    __syncthreads();

    int v = 0;
    if (t < RB) v = cnt[t];
    for (int off = 1; off < RB; off <<= 1) {
        int x = 0;
        if (t < RB && t >= off) x = cnt[t - off];
        __syncthreads();
        if (t < RB) cnt[t] += x;
        __syncthreads();
    }
    if (t < RB) {
        const int excl = cnt[t] - v;
        heads[t] = lo + excl;
        const int gr = rbase + t;
        if (gr <= N_NODES) row_ptr[gr] = lo + excl;
    }
    __syncthreads();

    for (int i = lo + t; i < hi; i += 512) {
        const float2 vc = svc[i];
        const int lr  = (int)(__float_as_uint(vc.y) >> 18);
        const int pos = atomicAdd(&heads[lr], 1);
        sedge[pos] = vc;
    }
}

// ===========================================================================
// Pull-SpMM over bf16 source (round-16 proven): dwordx4 gather, single
// predicated 16-wide loop, packed v2f accumulate (v_pk_fma_f32).
// ===========================================================================
__global__ __launch_bounds__(256) void spmm_bf16(
    const int* __restrict__ row_ptr,     // N_NODES+1
    const float2* __restrict__ sedge,    // (val, packed) row-sorted
    const u16* __restrict__ ebf,         // [N_NODES][64] bf16
    u16* __restrict__ tbf)               // [N_NODES][64] bf16
{
    const int tid  = threadIdx.x;
    const int lane = tid & 63;
    const int row  = blockIdx.x * 4 + (tid >> 6);
    if (row >= N_NODES) return;

    const int g = lane >> 3;    // edge slot 0..7
    const int q = lane & 7;     // feature octet -> features 8q..8q+7

    const int beg = row_ptr[row];
    const int end = row_ptr[row + 1];

    v2f A0 = {0.f, 0.f}, A1 = {0.f, 0.f}, A2 = {0.f, 0.f}, A3 = {0.f, 0.f};

    for (int k = beg; k < end; k += 16) {
        const int  kA  = k + g;
        const int  kB  = k + 8 + g;
        const bool onA = kA < end;
        const bool onB = kB < end;
        const float2 mA = sedge[onA ? kA : end - 1];
        const float2 mB = sedge[onB ? kB : end - 1];
        const float vA = onA ? mA.x : 0.f;
        const float vB = onB ? mB.x : 0.f;
        const u32 iA = __float_as_uint(mA.y) & COL_MASK;
        const u32 iB = __float_as_uint(mB.y) & COL_MASK;
        const uint4 xA = *((const uint4*)(ebf + (size_t)iA * EMB) + q);
        const uint4 xB = *((const uint4*)(ebf + (size_t)iB * EMB) + q);
        const v2f vvA = {vA, vA};
        const v2f vvB = {vB, vB};
        A0 = vvA * up2(xA.x) + A0;
        A1 = vvA * up2(xA.y) + A1;
        A2 = vvA * up2(xA.z) + A2;
        A3 = vvA * up2(xA.w) + A3;
        A0 = vvB * up2(xB.x) + A0;
        A1 = vvB * up2(xB.y) + A1;
        A2 = vvB * up2(xB.z) + A2;
        A3 = vvB * up2(xB.w) + A3;
    }

    // reduce across the 8 edge slots (xor 8,16,32) per f32 component
    float s0 = A0.x, s1 = A0.y, s2 = A1.x, s3 = A1.y;
    float s4 = A2.x, s5 = A2.y, s6 = A3.x, s7 = A3.y;
    s0 += __shfl_xor(s0, 8); s0 += __shfl_xor(s0, 16); s0 += __shfl_xor(s0, 32);
    s1 += __shfl_xor(s1, 8); s1 += __shfl_xor(s1, 16); s1 += __shfl_xor(s1, 32);
    s2 += __shfl_xor(s2, 8); s2 += __shfl_xor(s2, 16); s2 += __shfl_xor(s2, 32);
    s3 += __shfl_xor(s3, 8); s3 += __shfl_xor(s3, 16); s3 += __shfl_xor(s3, 32);
    s4 += __shfl_xor(s4, 8); s4 += __shfl_xor(s4, 16); s4 += __shfl_xor(s4, 32);
    s5 += __shfl_xor(s5, 8); s5 += __shfl_xor(s5, 16); s5 += __shfl_xor(s5, 32);
    s6 += __shfl_xor(s6, 8); s6 += __shfl_xor(s6, 16); s6 += __shfl_xor(s6, 32);
    s7 += __shfl_xor(s7, 8); s7 += __shfl_xor(s7, 16); s7 += __shfl_xor(s7, 32);

    if (g == 0) {
        uint4 w;
        w.x = pack_bf16(s0, s1);
        w.y = pack_bf16(s2, s3);
        w.z = pack_bf16(s4, s5);
        w.w = pack_bf16(s6, s7);
        *(uint4*)(tbf + (size_t)row * EMB + 8 * q) = w;
    }
}

// ===========================================================================
// Dense stage via MFMA: e1 = t @ W^T fused with LeakyReLU + mean-accum.
// FIRST: obf = bf16(0.25*(e0+e1+e2)), e2 -> ebf.  (no f32 out traffic)
// !FIRST: out = f32(obf) + 0.25*e3   (single f32 write of d_out)
// ===========================================================================
template <bool FIRST>
__global__ __launch_bounds__(256) void dense_mfma(
    const u16* __restrict__ tbf,     // [N_NODES][64] bf16
    const u16* __restrict__ Wbf,     // [64][64] bf16
    u16* ebf,                        // FIRST: e0 read + e2 write (same elem)
    u16* __restrict__ obf,           // partial mean, bf16
    float* __restrict__ out)
{
    const int tid  = threadIdx.x;
    const int l    = tid & 63;
    const int tile = blockIdx.x * 4 + (tid >> 6);
    if (tile >= NTILE) return;
    const int row0 = tile * 16;

    const int lr = l & 15;
    const int lk = l >> 4;

    short8v bfrag[4][2];
    #pragma unroll
    for (int c = 0; c < 4; ++c)
        #pragma unroll
        for (int kh = 0; kh < 2; ++kh)
            bfrag[c][kh] = *(const short8v*)(Wbf + (size_t)(16 * c + lr) * EMB
                                             + 32 * kh + 8 * lk);

    const u16* trow = tbf + (size_t)(row0 + lr) * EMB;
    const short8v afrag0 = *(const short8v*)(trow + 8 * lk);
    const short8v afrag1 = *(const short8v*)(trow + 32 + 8 * lk);

    f32x4 acc[4];
    #pragma unroll
    for (int c = 0; c < 4; ++c) {
        f32x4 z = {0.f, 0.f, 0.f, 0.f};
        z = __builtin_amdgcn_mfma_f32_16x16x32_bf16(afrag0, bfrag[c][0], z, 0, 0, 0);
        z = __builtin_amdgcn_mfma_f32_16x16x32_bf16(afrag1, bfrag[c][1], z, 0, 0, 0);
        acc[c] = z;
    }

    #pragma unroll
    for (int c = 0; c < 4; ++c) {
        #pragma unroll
        for (int r = 0; r < 4; ++r) {
            const int row = row0 + 4 * lk + r;
            const size_t idx = (size_t)row * EMB + 16 * c + lr;
            const float e1v = acc[c][r];
            if (FIRST) {
                const float e2v = (e1v >= 0.f) ? e1v : LEAKY * e1v;
                const float e0v = bf16_lo((u32)ebf[idx]);   // e0 (bf16)
                obf[idx] = f32_to_bf16_rne(0.25f * (e0v + e1v + e2v));
                ebf[idx] = f32_to_bf16_rne(e2v);            // e2 for stage 2
            } else {
                out[idx] = bf16_lo((u32)obf[idx]) + 0.25f * e1v;
            }
        }
    }
}

// ===========================================================================
// Fallback (round-1 proven): atomic SpMM + f32 dense, if ws too small.
// ===========================================================================
__global__ __launch_bounds__(256) void spmm_atomic(
    const float* __restrict__ vals, const int* __restrict__ rows,
    const int* __restrict__ cols, const float* __restrict__ src_a,
    const float* __restrict__ src_b, float* __restrict__ dst)
{
    const int tid  = threadIdx.x;
    const int lane = tid & 63;
    const int e    = blockIdx.x * 4 + (tid >> 6);
    if (e >= N_EDGES) return;
    const float v = vals[e];
    const int   c = cols[e];
    const int   r = rows[e];
    const float* src = (src_b != nullptr && c >= N_USERS)
                           ? src_b + (size_t)(c - N_USERS) * EMB
                           : src_a + (size_t)c * EMB;
    unsafeAtomicAdd(&dst[(size_t)r * EMB + lane], v * src[lane]);
}

template <bool FIRST>
__global__ __launch_bounds__(256) void dense_f32(
    const float* __restrict__ t, const float* __restrict__ W,
    const float* __restrict__ user_emb, const float* __restrict__ item_emb,
    float* __restrict__ e2, float* __restrict__ out)
{
    __shared__ float wT[64][65];
    __shared__ float trow[16][64];

    const int tid = threadIdx.x;
    for (int k = tid; k < 64 * 64; k += 256) {
        const int i = k >> 6, j = k & 63;
        wT[j][i] = W[k];
    }
    const int row_base = blockIdx.x * 16;
    for (int k = tid; k < 16 * 64; k += 256) {
        const int r = k >> 6, j = k & 63;
        const int row = row_base + r;
        trow[r][j] = (row < N_NODES) ? t[(size_t)row * EMB + j] : 0.f;
    }
    __syncthreads();

    const int i  = tid & 63;
    const int r0 = tid >> 6;

    #pragma unroll
    for (int rr = 0; rr < 4; ++rr) {
        const int r   = r0 * 4 + rr;
        const int row = row_base + r;
        if (row >= N_NODES) continue;
        float acc = 0.f;
        #pragma unroll
        for (int j = 0; j < 64; ++j)
            acc = fmaf(trow[r][j], wT[j][i], acc);
        const size_t idx = (size_t)row * EMB + i;
        if (FIRST) {
            const float e1v = acc;
            const float e2v = (e1v >= 0.f) ? e1v : LEAKY * e1v;
            const float e0v = (row < N_USERS)
                                  ? user_emb[idx]
                                  : item_emb[(size_t)(row - N_USERS) * EMB + i];
            e2[idx]  = e2v;
            out[idx] = 0.25f * (e0v + e1v + e2v);
        } else {
            out[idx] += 0.25f * acc;
        }
    }
}

// ===========================================================================
extern "C" void kernel_launch(void* const* d_in, const int* in_sizes, int n_in,
                              void* d_out, int out_size, void* d_ws, size_t ws_size,
                              hipStream_t stream)
{
    const float* user_emb = (const float*)d_in[0];
    const float* item_emb = (const float*)d_in[1];
    const float* W0       = (const float*)d_in[2];
    const float* W1       = (const float*)d_in[3];
    const float* adj_vals = (const float*)d_in[4];
    const int*   adj_rows = (const int*)d_in[5];
    const int*   adj_cols = (const int*)d_in[6];
    float*       out      = (float*)d_out;

    const size_t mat_bytes = (size_t)N_NODES * EMB * sizeof(float);   // 38.4 MB
    const size_t ebf_bytes = (size_t)N_NODES * EMB * sizeof(u16);     // 19.2 MB
    const size_t edge8     = (size_t)N_EDGES * sizeof(float2);        // 19.2 MB
    const size_t hmat      = (size_t)NCH * NBKT * sizeof(int);        // 0.34 MB

    // layout: [tbf | svc transient] [sedge] [ebf] [obf] [aux] [Wbf]
    const size_t off_tbf    = 0;
    const size_t off_svc    = 0;                       // transient, inside tbf
    const size_t off_sedge  = off_tbf + ebf_bytes;
    const size_t off_ebf    = off_sedge + edge8;
    const size_t off_obf    = off_ebf + ebf_bytes;
    const size_t off_rowptr = off_obf + ebf_bytes;
    const size_t off_H      = off_rowptr + (size_t)(N_NODES + 1) * sizeof(int);
    const size_t off_B      = off_H + hmat;
    const size_t off_ptr    = off_B + hmat;
    const size_t off_wbf    = (off_ptr + (size_t)(NBKT + 1) * sizeof(int) + 15) & ~(size_t)15;
    const size_t required   = off_wbf + 2 * (size_t)EMB * EMB * sizeof(u16); // ~79 MB

    const int spmm_blocks   = (N_NODES + 3) / 4;       // 37500
    const int densem_blocks = (NTILE + 3) / 4;         // 2344
    const int conv_blocks   = (N_NODES * EMB / 4 + 255) / 256;

    if (ws_size >= required) {
        u16*    tbf     = (u16*)((char*)d_ws + off_tbf);
        float2* svc     = (float2*)((char*)d_ws + off_svc);
        float2* sedge   = (float2*)((char*)d_ws + off_sedge);
        u16*    ebf     = (u16*)((char*)d_ws + off_ebf);
        u16*    obf     = (u16*)((char*)d_ws + off_obf);
        int*    row_ptr = (int*)((char*)d_ws + off_rowptr);
        int*    H       = (int*)((char*)d_ws + off_H);
        int*    B       = (int*)((char*)d_ws + off_B);
        int*    bkt_ptr = (int*)((char*)d_ws + off_ptr);
        u16*    Wbf0    = (u16*)((char*)d_ws + off_wbf);
        u16*    Wbf1    = Wbf0 + EMB * EMB;

        // ---- bf16 sources (e0, W0, W1) ----
        conv_all<<<conv_blocks, 256, 0, stream>>>(
            user_emb, item_emb, W0, W1, ebf, Wbf0, Wbf1);

        // ---- bucket-sorted edge list + row_ptr (once, reused twice) ----
        bkt_hist<<<NCH, 1024, 0, stream>>>(adj_rows, H);
        scan_bkt<<<1, 1024, 0, stream>>>(H, bkt_ptr);
        fill_B<<<(NBKT + 255) / 256, 256, 0, stream>>>(H, bkt_ptr, B);
        partition_l1<<<NCH, 1024, 0, stream>>>(
            adj_vals, adj_rows, adj_cols, B, svc);
        place_l2<<<NBKT, 512, 0, stream>>>(bkt_ptr, svc, sedge, row_ptr);
        // svc (inside tbf) is dead from here on

        // ---- stage 1: tbf = A @ e0 ; obf = 0.25(e0+e1+e2) ; e2 -> ebf ----
        spmm_bf16<<<spmm_blocks, 256, 0, stream>>>(row_ptr, sedge, ebf, tbf);
        dense_mfma<true><<<densem_blocks, 256, 0, stream>>>(
            tbf, Wbf0, ebf, obf, out);

        // ---- stage 2: tbf = A @ e2 ; out = obf + 0.25*e3 ----
        spmm_bf16<<<spmm_blocks, 256, 0, stream>>>(row_ptr, sedge, ebf, tbf);
        dense_mfma<false><<<densem_blocks, 256, 0, stream>>>(
            tbf, Wbf1, ebf, obf, out);
    } else {
        // ---- fallback: round-1 atomic path ----
        float* t  = (float*)d_ws;
        float* e2 = (float*)((char*)d_ws + mat_bytes);
        const int dense_blocks = (N_NODES + 15) / 16;

        hipMemsetAsync(t, 0, mat_bytes, stream);
        spmm_atomic<<<(N_EDGES + 3) / 4, 256, 0, stream>>>(
            adj_vals, adj_rows, adj_cols, user_emb, item_emb, t);
        dense_f32<true><<<dense_blocks, 256, 0, stream>>>(
            t, W0, user_emb, item_emb, e2, out);

        hipMemsetAsync(t, 0, mat_bytes, stream);
        spmm_atomic<<<(N_EDGES + 3) / 4, 256, 0, stream>>>(
            adj_vals, adj_rows, adj_cols, e2, nullptr, t);
        dense_f32<false><<<dense_blocks, 256, 0, stream>>>(
            t, W1, nullptr, nullptr, nullptr, out);
    }
}

// Round 21
// 209.206 us; speedup vs baseline: 1.3260x; 1.0622x over previous
//
#include <hip/hip_runtime.h>

#define N_USERS 100000
#define N_ITEMS 50000
#define N_NODES 150000
#define N_EDGES 2400000
#define EMB 64
#define LEAKY 0.3f

#define RB_SHIFT 8                                         // 256 rows / bucket
#define RB (1 << RB_SHIFT)
#define NBKT ((N_NODES + RB - 1) >> RB_SHIFT)              // 586
#define L1_CHUNK 16384
#define NCH ((N_EDGES + L1_CHUNK - 1) / L1_CHUNK)          // 147 chunks
#define COL_MASK 0x3FFFFu                                  // col < 2^18
#define NTILE (N_NODES / 16)                               // 9375 (exact)
#define PCAP 6144                                          // place LDS capacity

typedef unsigned short u16;
typedef unsigned int   u32;
typedef __attribute__((ext_vector_type(8))) short short8v;
typedef __attribute__((ext_vector_type(4))) float f32x4;
typedef __attribute__((ext_vector_type(2))) float v2f;

__device__ __forceinline__ u16 f32_to_bf16_rne(float f) {
    u32 u = __float_as_uint(f);
    u32 r = (u + 0x7FFFu + ((u >> 16) & 1u)) >> 16;
    return (u16)r;
}
__device__ __forceinline__ float bf16_lo(u32 x) { return __uint_as_float(x << 16); }
__device__ __forceinline__ u32 pack_bf16(float lo, float hi) {
    return (u32)f32_to_bf16_rne(lo) | ((u32)f32_to_bf16_rne(hi) << 16);
}
// unpack a bf16-pair dword into a packed f32 pair (feeds v_pk_fma_f32)
__device__ __forceinline__ v2f up2(u32 w) {
    v2f r;
    r.x = __uint_as_float(w << 16);
    r.y = __uint_as_float(w & 0xFFFF0000u);
    return r;
}

// ===========================================================================
// conv_hist: blocks [0,NCH) = per-chunk bucket histogram; remaining blocks
// convert e0 (and W0/W1) to bf16. Latency-bound hist hides under BW conv.
// ===========================================================================
__global__ __launch_bounds__(1024) void conv_hist(
    const float* __restrict__ uemb, const float* __restrict__ iemb,
    const float* __restrict__ W0, const float* __restrict__ W1,
    const int* __restrict__ rows,
    u16* __restrict__ ebf, u16* __restrict__ Wbf0, u16* __restrict__ Wbf1,
    int* __restrict__ H)
{
    __shared__ int cnt[NBKT];
    const int t = threadIdx.x;
    const int b = blockIdx.x;

    if (b < NCH) {
        if (t < NBKT) cnt[t] = 0;
        __syncthreads();
        const int e0 = b * L1_CHUNK;
        const int e1 = (e0 + L1_CHUNK < N_EDGES) ? e0 + L1_CHUNK : N_EDGES;
        for (int i = e0 + t; i < e1; i += 1024)
            atomicAdd(&cnt[rows[i] >> RB_SHIFT], 1);
        __syncthreads();
        if (t < NBKT) H[b * NBKT + t] = cnt[t];
    } else {
        const int gid = (b - NCH) * 1024 + t;
        const int i = gid * 4;
        if (i < N_NODES * EMB) {
            const float* src = (i < N_USERS * EMB) ? uemb + i
                                                   : iemb + (i - N_USERS * EMB);
            const float4 v = *(const float4*)src;
            ushort4 w;
            w.x = f32_to_bf16_rne(v.x);
            w.y = f32_to_bf16_rne(v.y);
            w.z = f32_to_bf16_rne(v.z);
            w.w = f32_to_bf16_rne(v.w);
            *(ushort4*)(ebf + i) = w;
        }
        if (gid < EMB * EMB) {
            Wbf0[gid] = f32_to_bf16_rne(W0[gid]);
            Wbf1[gid] = f32_to_bf16_rne(W1[gid]);
        }
    }
}

// ===========================================================================
// scan_fill (single block, 1024 thr): bucket totals (4-chunk unroll) ->
// LDS exclusive scan -> bkt_ptr; then thread t fills B[.][t] (4-unrolled).
// ===========================================================================
__global__ __launch_bounds__(1024) void scan_fill(
    const int* __restrict__ H, int* __restrict__ bkt_ptr,
    int* __restrict__ B)
{
    __shared__ int lds[1024];
    const int t = threadIdx.x;

    int tot = 0;
    if (t < NBKT) {
        int a0 = 0, a1 = 0, a2 = 0, a3 = 0;
        int c = 0;
        for (; c + 4 <= NCH; c += 4) {      // 4 independent loads / iter
            a0 += H[(c + 0) * NBKT + t];
            a1 += H[(c + 1) * NBKT + t];
            a2 += H[(c + 2) * NBKT + t];
            a3 += H[(c + 3) * NBKT + t];
        }
        for (; c < NCH; ++c) a0 += H[c * NBKT + t];
        tot = (a0 + a1) + (a2 + a3);
    }
    lds[t] = (t < NBKT) ? tot : 0;
    __syncthreads();
    for (int off = 1; off < 1024; off <<= 1) {
        int x = 0;
        if (t >= off) x = lds[t - off];
        __syncthreads();
        lds[t] += x;
        __syncthreads();
    }
    const int excl = lds[t] - tot;

    if (t < NBKT) {
        bkt_ptr[t] = excl;
        int run = excl;
        int c = 0;
        for (; c + 4 <= NCH; c += 4) {       // 4 loads in flight
            const int h0 = H[(c + 0) * NBKT + t];
            const int h1 = H[(c + 1) * NBKT + t];
            const int h2 = H[(c + 2) * NBKT + t];
            const int h3 = H[(c + 3) * NBKT + t];
            B[(c + 0) * NBKT + t] = run;
            B[(c + 1) * NBKT + t] = run + h0;
            B[(c + 2) * NBKT + t] = run + h0 + h1;
            B[(c + 3) * NBKT + t] = run + h0 + h1 + h2;
            run += h0 + h1 + h2 + h3;
        }
        for (; c < NCH; ++c) {
            B[c * NBKT + t] = run;
            run += H[c * NBKT + t];
        }
    }
    if (t == 0) bkt_ptr[NBKT] = N_EDGES;
}

// ===========================================================================
// Partition (single edge pass, no global atomics)
// record = (val, (localrow<<18)|col), localrow 8 bits
// ===========================================================================
__global__ __launch_bounds__(1024) void partition_l1(
    const float* __restrict__ vals, const int* __restrict__ rows,
    const int* __restrict__ cols, const int* __restrict__ B,
    float2* __restrict__ svc)
{
    __shared__ int base[NBKT];
    __shared__ int cnt[NBKT];
    const int t = threadIdx.x;
    const int c = blockIdx.x;
    if (t < NBKT) {
        base[t] = B[c * NBKT + t];
        cnt[t]  = 0;
    }
    __syncthreads();

    const int e0 = c * L1_CHUNK;
    const int e1 = (e0 + L1_CHUNK < N_EDGES) ? e0 + L1_CHUNK : N_EDGES;
    for (int i = e0 + t; i < e1; i += 1024) {
        const int r = rows[i];
        const int b = r >> RB_SHIFT;
        const int pos = base[b] + atomicAdd(&cnt[b], 1);
        const u32 packed = ((u32)(r & (RB - 1)) << 18) | (u32)cols[i];
        svc[pos] = make_float2(vals[i], __uint_as_float(packed));
    }
}

// ===========================================================================
// place_l2: count (LDS) -> scan -> row_ptr -> place into LDS buffer ->
// stream out COALESCED (no scattered global writes, no L2-line reliance).
// Fallback to scattered-global path if a bucket exceeds PCAP (statistically
// impossible for uniform rows: mean 4096, sigma 64).
// ===========================================================================
__global__ __launch_bounds__(512) void place_l2(
    const int* __restrict__ bkt_ptr, const float2* __restrict__ svc,
    float2* __restrict__ sedge, int* __restrict__ row_ptr)
{
    __shared__ float2 E2[PCAP];    // 48 KB
    __shared__ int cnt[RB];
    __shared__ int heads[RB];      // local (0-based within bucket)
    const int b     = blockIdx.x;
    const int rbase = b << RB_SHIFT;
    const int t     = threadIdx.x;

    if (t < RB) cnt[t] = 0;
    __syncthreads();

    const int lo = bkt_ptr[b];
    const int hi = bkt_ptr[b + 1];
    const int n  = hi - lo;

    for (int i = lo + t; i < hi; i += 512)
        atomicAdd(&cnt[__float_as_uint(svc[i].y) >> 18], 1);
    __syncthreads();

    int v = 0;
    if (t < RB) v = cnt[t];
    for (int off = 1; off < RB; off <<= 1) {
        int x = 0;
        if (t < RB && t >= off) x = cnt[t - off];
        __syncthreads();
        if (t < RB) cnt[t] += x;
        __syncthreads();
    }
    if (t < RB) {
        const int excl = cnt[t] - v;
        heads[t] = excl;                       // local base
        const int gr = rbase + t;
        if (gr <= N_NODES) row_ptr[gr] = lo + excl;
    }
    __syncthreads();

    if (n <= PCAP) {
        for (int i = lo + t; i < hi; i += 512) {
            const float2 vc = svc[i];
            const int lr  = (int)(__float_as_uint(vc.y) >> 18);
            const int pos = atomicAdd(&heads[lr], 1);
            E2[pos] = vc;
        }
        __syncthreads();
        for (int i = t; i < n; i += 512)       // coalesced streaming store
            sedge[lo + i] = E2[i];
    } else {
        for (int i = lo + t; i < hi; i += 512) {
            const float2 vc = svc[i];
            const int lr  = (int)(__float_as_uint(vc.y) >> 18);
            const int pos = atomicAdd(&heads[lr], 1);
            sedge[lo + pos] = vc;
        }
    }
}

// ===========================================================================
// Pull-SpMM over bf16 source (round-16 proven): dwordx4 gather, single
// predicated 16-wide loop, packed v2f accumulate (v_pk_fma_f32).
// ===========================================================================
__global__ __launch_bounds__(256) void spmm_bf16(
    const int* __restrict__ row_ptr,     // N_NODES+1
    const float2* __restrict__ sedge,    // (val, packed) row-sorted
    const u16* __restrict__ ebf,         // [N_NODES][64] bf16
    u16* __restrict__ tbf)               // [N_NODES][64] bf16
{
    const int tid  = threadIdx.x;
    const int lane = tid & 63;
    const int row  = blockIdx.x * 4 + (tid >> 6);
    if (row >= N_NODES) return;

    const int g = lane >> 3;    // edge slot 0..7
    const int q = lane & 7;     // feature octet -> features 8q..8q+7

    const int beg = row_ptr[row];
    const int end = row_ptr[row + 1];

    v2f A0 = {0.f, 0.f}, A1 = {0.f, 0.f}, A2 = {0.f, 0.f}, A3 = {0.f, 0.f};

    for (int k = beg; k < end; k += 16) {
        const int  kA  = k + g;
        const int  kB  = k + 8 + g;
        const bool onA = kA < end;
        const bool onB = kB < end;
        const float2 mA = sedge[onA ? kA : end - 1];
        const float2 mB = sedge[onB ? kB : end - 1];
        const float vA = onA ? mA.x : 0.f;
        const float vB = onB ? mB.x : 0.f;
        const u32 iA = __float_as_uint(mA.y) & COL_MASK;
        const u32 iB = __float_as_uint(mB.y) & COL_MASK;
        const uint4 xA = *((const uint4*)(ebf + (size_t)iA * EMB) + q);
        const uint4 xB = *((const uint4*)(ebf + (size_t)iB * EMB) + q);
        const v2f vvA = {vA, vA};
        const v2f vvB = {vB, vB};
        A0 = vvA * up2(xA.x) + A0;
        A1 = vvA * up2(xA.y) + A1;
        A2 = vvA * up2(xA.z) + A2;
        A3 = vvA * up2(xA.w) + A3;
        A0 = vvB * up2(xB.x) + A0;
        A1 = vvB * up2(xB.y) + A1;
        A2 = vvB * up2(xB.z) + A2;
        A3 = vvB * up2(xB.w) + A3;
    }

    // reduce across the 8 edge slots (xor 8,16,32) per f32 component
    float s0 = A0.x, s1 = A0.y, s2 = A1.x, s3 = A1.y;
    float s4 = A2.x, s5 = A2.y, s6 = A3.x, s7 = A3.y;
    s0 += __shfl_xor(s0, 8); s0 += __shfl_xor(s0, 16); s0 += __shfl_xor(s0, 32);
    s1 += __shfl_xor(s1, 8); s1 += __shfl_xor(s1, 16); s1 += __shfl_xor(s1, 32);
    s2 += __shfl_xor(s2, 8); s2 += __shfl_xor(s2, 16); s2 += __shfl_xor(s2, 32);
    s3 += __shfl_xor(s3, 8); s3 += __shfl_xor(s3, 16); s3 += __shfl_xor(s3, 32);
    s4 += __shfl_xor(s4, 8); s4 += __shfl_xor(s4, 16); s4 += __shfl_xor(s4, 32);
    s5 += __shfl_xor(s5, 8); s5 += __shfl_xor(s5, 16); s5 += __shfl_xor(s5, 32);
    s6 += __shfl_xor(s6, 8); s6 += __shfl_xor(s6, 16); s6 += __shfl_xor(s6, 32);
    s7 += __shfl_xor(s7, 8); s7 += __shfl_xor(s7, 16); s7 += __shfl_xor(s7, 32);

    if (g == 0) {
        uint4 w;
        w.x = pack_bf16(s0, s1);
        w.y = pack_bf16(s2, s3);
        w.z = pack_bf16(s4, s5);
        w.w = pack_bf16(s6, s7);
        *(uint4*)(tbf + (size_t)row * EMB + 8 * q) = w;
    }
}

// ===========================================================================
// Dense stage via MFMA: e1 = t @ W^T fused with LeakyReLU + mean-accum.
// FIRST: obf = bf16(0.25*(e0+e1+e2)), e2 -> ebf.  (no f32 out traffic)
// !FIRST: out = f32(obf) + 0.25*e3   (single f32 write of d_out)
// ===========================================================================
template <bool FIRST>
__global__ __launch_bounds__(256) void dense_mfma(
    const u16* __restrict__ tbf,     // [N_NODES][64] bf16
    const u16* __restrict__ Wbf,     // [64][64] bf16
    u16* ebf,                        // FIRST: e0 read + e2 write (same elem)
    u16* __restrict__ obf,           // partial mean, bf16
    float* __restrict__ out)
{
    const int tid  = threadIdx.x;
    const int l    = tid & 63;
    const int tile = blockIdx.x * 4 + (tid >> 6);
    if (tile >= NTILE) return;
    const int row0 = tile * 16;

    const int lr = l & 15;
    const int lk = l >> 4;

    short8v bfrag[4][2];
    #pragma unroll
    for (int c = 0; c < 4; ++c)
        #pragma unroll
        for (int kh = 0; kh < 2; ++kh)
            bfrag[c][kh] = *(const short8v*)(Wbf + (size_t)(16 * c + lr) * EMB
                                             + 32 * kh + 8 * lk);

    const u16* trow = tbf + (size_t)(row0 + lr) * EMB;
    const short8v afrag0 = *(const short8v*)(trow + 8 * lk);
    const short8v afrag1 = *(const short8v*)(trow + 32 + 8 * lk);

    f32x4 acc[4];
    #pragma unroll
    for (int c = 0; c < 4; ++c) {
        f32x4 z = {0.f, 0.f, 0.f, 0.f};
        z = __builtin_amdgcn_mfma_f32_16x16x32_bf16(afrag0, bfrag[c][0], z, 0, 0, 0);
        z = __builtin_amdgcn_mfma_f32_16x16x32_bf16(afrag1, bfrag[c][1], z, 0, 0, 0);
        acc[c] = z;
    }

    #pragma unroll
    for (int c = 0; c < 4; ++c) {
        #pragma unroll
        for (int r = 0; r < 4; ++r) {
            const int row = row0 + 4 * lk + r;
            const size_t idx = (size_t)row * EMB + 16 * c + lr;
            const float e1v = acc[c][r];
            if (FIRST) {
                const float e2v = (e1v >= 0.f) ? e1v : LEAKY * e1v;
                const float e0v = bf16_lo((u32)ebf[idx]);   // e0 (bf16)
                obf[idx] = f32_to_bf16_rne(0.25f * (e0v + e1v + e2v));
                ebf[idx] = f32_to_bf16_rne(e2v);            // e2 for stage 2
            } else {
                out[idx] = bf16_lo((u32)obf[idx]) + 0.25f * e1v;
            }
        }
    }
}

// ===========================================================================
// Fallback (round-1 proven): atomic SpMM + f32 dense, if ws too small.
// ===========================================================================
__global__ __launch_bounds__(256) void spmm_atomic(
    const float* __restrict__ vals, const int* __restrict__ rows,
    const int* __restrict__ cols, const float* __restrict__ src_a,
    const float* __restrict__ src_b, float* __restrict__ dst)
{
    const int tid  = threadIdx.x;
    const int lane = tid & 63;
    const int e    = blockIdx.x * 4 + (tid >> 6);
    if (e >= N_EDGES) return;
    const float v = vals[e];
    const int   c = cols[e];
    const int   r = rows[e];
    const float* src = (src_b != nullptr && c >= N_USERS)
                           ? src_b + (size_t)(c - N_USERS) * EMB
                           : src_a + (size_t)c * EMB;
    unsafeAtomicAdd(&dst[(size_t)r * EMB + lane], v * src[lane]);
}

template <bool FIRST>
__global__ __launch_bounds__(256) void dense_f32(
    const float* __restrict__ t, const float* __restrict__ W,
    const float* __restrict__ user_emb, const float* __restrict__ item_emb,
    float* __restrict__ e2, float* __restrict__ out)
{
    __shared__ float wT[64][65];
    __shared__ float trow[16][64];

    const int tid = threadIdx.x;
    for (int k = tid; k < 64 * 64; k += 256) {
        const int i = k >> 6, j = k & 63;
        wT[j][i] = W[k];
    }
    const int row_base = blockIdx.x * 16;
    for (int k = tid; k < 16 * 64; k += 256) {
        const int r = k >> 6, j = k & 63;
        const int row = row_base + r;
        trow[r][j] = (row < N_NODES) ? t[(size_t)row * EMB + j] : 0.f;
    }
    __syncthreads();

    const int i  = tid & 63;
    const int r0 = tid >> 6;

    #pragma unroll
    for (int rr = 0; rr < 4; ++rr) {
        const int r   = r0 * 4 + rr;
        const int row = row_base + r;
        if (row >= N_NODES) continue;
        float acc = 0.f;
        #pragma unroll
        for (int j = 0; j < 64; ++j)
            acc = fmaf(trow[r][j], wT[j][i], acc);
        const size_t idx = (size_t)row * EMB + i;
        if (FIRST) {
            const float e1v = acc;
            const float e2v = (e1v >= 0.f) ? e1v : LEAKY * e1v;
            const float e0v = (row < N_USERS)
                                  ? user_emb[idx]
                                  : item_emb[(size_t)(row - N_USERS) * EMB + i];
            e2[idx]  = e2v;
            out[idx] = 0.25f * (e0v + e1v + e2v);
        } else {
            out[idx] += 0.25f * acc;
        }
    }
}

// ===========================================================================
extern "C" void kernel_launch(void* const* d_in, const int* in_sizes, int n_in,
                              void* d_out, int out_size, void* d_ws, size_t ws_size,
                              hipStream_t stream)
{
    const float* user_emb = (const float*)d_in[0];
    const float* item_emb = (const float*)d_in[1];
    const float* W0       = (const float*)d_in[2];
    const float* W1       = (const float*)d_in[3];
    const float* adj_vals = (const float*)d_in[4];
    const int*   adj_rows = (const int*)d_in[5];
    const int*   adj_cols = (const int*)d_in[6];
    float*       out      = (float*)d_out;

    const size_t mat_bytes = (size_t)N_NODES * EMB * sizeof(float);   // 38.4 MB
    const size_t ebf_bytes = (size_t)N_NODES * EMB * sizeof(u16);     // 19.2 MB
    const size_t edge8     = (size_t)N_EDGES * sizeof(float2);        // 19.2 MB
    const size_t hmat      = (size_t)NCH * NBKT * sizeof(int);        // 0.34 MB

    // layout: [tbf | svc transient] [sedge] [ebf] [obf] [aux] [Wbf]
    const size_t off_tbf    = 0;
    const size_t off_svc    = 0;                       // transient, inside tbf
    const size_t off_sedge  = off_tbf + ebf_bytes;
    const size_t off_ebf    = off_sedge + edge8;
    const size_t off_obf    = off_ebf + ebf_bytes;
    const size_t off_rowptr = off_obf + ebf_bytes;
    const size_t off_H      = off_rowptr + (size_t)(N_NODES + 1) * sizeof(int);
    const size_t off_B      = off_H + hmat;
    const size_t off_ptr    = off_B + hmat;
    const size_t off_wbf    = (off_ptr + (size_t)(NBKT + 1) * sizeof(int) + 15) & ~(size_t)15;
    const size_t required   = off_wbf + 2 * (size_t)EMB * EMB * sizeof(u16); // ~79 MB

    const int spmm_blocks   = (N_NODES + 3) / 4;       // 37500
    const int densem_blocks = (NTILE + 3) / 4;         // 2344
    const int convh_blocks  = NCH + (N_NODES * EMB / 4 + 1023) / 1024;  // 147+2344

    if (ws_size >= required) {
        u16*    tbf     = (u16*)((char*)d_ws + off_tbf);
        float2* svc     = (float2*)((char*)d_ws + off_svc);
        float2* sedge   = (float2*)((char*)d_ws + off_sedge);
        u16*    ebf     = (u16*)((char*)d_ws + off_ebf);
        u16*    obf     = (u16*)((char*)d_ws + off_obf);
        int*    row_ptr = (int*)((char*)d_ws + off_rowptr);
        int*    H       = (int*)((char*)d_ws + off_H);
        int*    B       = (int*)((char*)d_ws + off_B);
        int*    bkt_ptr = (int*)((char*)d_ws + off_ptr);
        u16*    Wbf0    = (u16*)((char*)d_ws + off_wbf);
        u16*    Wbf1    = Wbf0 + EMB * EMB;

        // ---- bf16 sources + bucket histogram (one dispatch) ----
        conv_hist<<<convh_blocks, 1024, 0, stream>>>(
            user_emb, item_emb, W0, W1, adj_rows, ebf, Wbf0, Wbf1, H);

        // ---- bucket-sorted edge list + row_ptr (once, reused twice) ----
        scan_fill<<<1, 1024, 0, stream>>>(H, bkt_ptr, B);
        partition_l1<<<NCH, 1024, 0, stream>>>(
            adj_vals, adj_rows, adj_cols, B, svc);
        place_l2<<<NBKT, 512, 0, stream>>>(bkt_ptr, svc, sedge, row_ptr);
        // svc (inside tbf) is dead from here on

        // ---- stage 1: tbf = A @ e0 ; obf = 0.25(e0+e1+e2) ; e2 -> ebf ----
        spmm_bf16<<<spmm_blocks, 256, 0, stream>>>(row_ptr, sedge, ebf, tbf);
        dense_mfma<true><<<densem_blocks, 256, 0, stream>>>(
            tbf, Wbf0, ebf, obf, out);

        // ---- stage 2: tbf = A @ e2 ; out = obf + 0.25*e3 ----
        spmm_bf16<<<spmm_blocks, 256, 0, stream>>>(row_ptr, sedge, ebf, tbf);
        dense_mfma<false><<<densem_blocks, 256, 0, stream>>>(
            tbf, Wbf1, ebf, obf, out);
    } else {
        // ---- fallback: round-1 atomic path ----
        float* t  = (float*)d_ws;
        float* e2 = (float*)((char*)d_ws + mat_bytes);
        const int dense_blocks = (N_NODES + 15) / 16;

        hipMemsetAsync(t, 0, mat_bytes, stream);
        spmm_atomic<<<(N_EDGES + 3) / 4, 256, 0, stream>>>(
            adj_vals, adj_rows, adj_cols, user_emb, item_emb, t);
        dense_f32<true><<<dense_blocks, 256, 0, stream>>>(
            t, W0, user_emb, item_emb, e2, out);

        hipMemsetAsync(t, 0, mat_bytes, stream);
        spmm_atomic<<<(N_EDGES + 3) / 4, 256, 0, stream>>>(
            adj_vals, adj_rows, adj_cols, e2, nullptr, t);
        dense_f32<false><<<dense_blocks, 256, 0, stream>>>(
            t, W1, nullptr, nullptr, nullptr, out);
    }
}

// Round 22
// 185.403 us; speedup vs baseline: 1.4963x; 1.1284x over previous
//
#include <hip/hip_runtime.h>

#define N_USERS 100000
#define N_ITEMS 50000
#define N_NODES 150000
#define N_EDGES 2400000
#define EMB 64
#define LEAKY 0.3f

#define RB_SHIFT 8                                         // 256 rows / bucket
#define RB (1 << RB_SHIFT)
#define NBKT ((N_NODES + RB - 1) >> RB_SHIFT)              // 586
#define L1_CHUNK 16384
#define NCH ((N_EDGES + L1_CHUNK - 1) / L1_CHUNK)          // 147 chunks
#define COL_MASK 0x3FFFFu                                  // col < 2^18
#define NTILE (N_NODES / 16)                               // 9375 (exact)
#define PCAP 6144                                          // place LDS capacity

typedef unsigned short u16;
typedef unsigned int   u32;
typedef __attribute__((ext_vector_type(8))) short short8v;
typedef __attribute__((ext_vector_type(4))) float f32x4;
typedef __attribute__((ext_vector_type(2))) float v2f;

__device__ __forceinline__ u16 f32_to_bf16_rne(float f) {
    u32 u = __float_as_uint(f);
    u32 r = (u + 0x7FFFu + ((u >> 16) & 1u)) >> 16;
    return (u16)r;
}
__device__ __forceinline__ float bf16_lo(u32 x) { return __uint_as_float(x << 16); }
__device__ __forceinline__ u32 pack_bf16(float lo, float hi) {
    return (u32)f32_to_bf16_rne(lo) | ((u32)f32_to_bf16_rne(hi) << 16);
}
__device__ __forceinline__ v2f up2(u32 w) {
    v2f r;
    r.x = __uint_as_float(w << 16);
    r.y = __uint_as_float(w & 0xFFFF0000u);
    return r;
}

// ===========================================================================
// conv_hist: blocks [0,NCH) = per-chunk bucket histogram; remaining blocks
// convert e0 (and W0/W1) to bf16. (round-21 proven)
// ===========================================================================
__global__ __launch_bounds__(1024) void conv_hist(
    const float* __restrict__ uemb, const float* __restrict__ iemb,
    const float* __restrict__ W0, const float* __restrict__ W1,
    const int* __restrict__ rows,
    u16* __restrict__ ebf, u16* __restrict__ Wbf0, u16* __restrict__ Wbf1,
    int* __restrict__ H)
{
    __shared__ int cnt[NBKT];
    const int t = threadIdx.x;
    const int b = blockIdx.x;

    if (b < NCH) {
        if (t < NBKT) cnt[t] = 0;
        __syncthreads();
        const int e0 = b * L1_CHUNK;
        const int e1 = (e0 + L1_CHUNK < N_EDGES) ? e0 + L1_CHUNK : N_EDGES;
        for (int i = e0 + t; i < e1; i += 1024)
            atomicAdd(&cnt[rows[i] >> RB_SHIFT], 1);
        __syncthreads();
        if (t < NBKT) H[b * NBKT + t] = cnt[t];
    } else {
        const int gid = (b - NCH) * 1024 + t;
        const int i = gid * 4;
        if (i < N_NODES * EMB) {
            const float* src = (i < N_USERS * EMB) ? uemb + i
                                                   : iemb + (i - N_USERS * EMB);
            const float4 v = *(const float4*)src;
            ushort4 w;
            w.x = f32_to_bf16_rne(v.x);
            w.y = f32_to_bf16_rne(v.y);
            w.z = f32_to_bf16_rne(v.z);
            w.w = f32_to_bf16_rne(v.w);
            *(ushort4*)(ebf + i) = w;
        }
        if (gid < EMB * EMB) {
            Wbf0[gid] = f32_to_bf16_rne(W0[gid]);
            Wbf1[gid] = f32_to_bf16_rne(W1[gid]);
        }
    }
}

// ===========================================================================
// scan_fill (single block, 1024 thr): bucket totals -> scan -> bkt_ptr ->
// per-(chunk,bucket) bases B. (round-21 proven)
// ===========================================================================
__global__ __launch_bounds__(1024) void scan_fill(
    const int* __restrict__ H, int* __restrict__ bkt_ptr,
    int* __restrict__ B)
{
    __shared__ int lds[1024];
    const int t = threadIdx.x;

    int tot = 0;
    if (t < NBKT) {
        int a0 = 0, a1 = 0, a2 = 0, a3 = 0;
        int c = 0;
        for (; c + 4 <= NCH; c += 4) {
            a0 += H[(c + 0) * NBKT + t];
            a1 += H[(c + 1) * NBKT + t];
            a2 += H[(c + 2) * NBKT + t];
            a3 += H[(c + 3) * NBKT + t];
        }
        for (; c < NCH; ++c) a0 += H[c * NBKT + t];
        tot = (a0 + a1) + (a2 + a3);
    }
    lds[t] = (t < NBKT) ? tot : 0;
    __syncthreads();
    for (int off = 1; off < 1024; off <<= 1) {
        int x = 0;
        if (t >= off) x = lds[t - off];
        __syncthreads();
        lds[t] += x;
        __syncthreads();
    }
    const int excl = lds[t] - tot;

    if (t < NBKT) {
        bkt_ptr[t] = excl;
        int run = excl;
        int c = 0;
        for (; c + 4 <= NCH; c += 4) {
            const int h0 = H[(c + 0) * NBKT + t];
            const int h1 = H[(c + 1) * NBKT + t];
            const int h2 = H[(c + 2) * NBKT + t];
            const int h3 = H[(c + 3) * NBKT + t];
            B[(c + 0) * NBKT + t] = run;
            B[(c + 1) * NBKT + t] = run + h0;
            B[(c + 2) * NBKT + t] = run + h0 + h1;
            B[(c + 3) * NBKT + t] = run + h0 + h1 + h2;
            run += h0 + h1 + h2 + h3;
        }
        for (; c < NCH; ++c) {
            B[c * NBKT + t] = run;
            run += H[c * NBKT + t];
        }
    }
    if (t == 0) bkt_ptr[NBKT] = N_EDGES;
}

// ===========================================================================
// Partition (single edge pass, no global atomics). (round-21 proven)
// ===========================================================================
__global__ __launch_bounds__(1024) void partition_l1(
    const float* __restrict__ vals, const int* __restrict__ rows,
    const int* __restrict__ cols, const int* __restrict__ B,
    float2* __restrict__ svc)
{
    __shared__ int base[NBKT];
    __shared__ int cnt[NBKT];
    const int t = threadIdx.x;
    const int c = blockIdx.x;
    if (t < NBKT) {
        base[t] = B[c * NBKT + t];
        cnt[t]  = 0;
    }
    __syncthreads();

    const int e0 = c * L1_CHUNK;
    const int e1 = (e0 + L1_CHUNK < N_EDGES) ? e0 + L1_CHUNK : N_EDGES;
    for (int i = e0 + t; i < e1; i += 1024) {
        const int r = rows[i];
        const int b = r >> RB_SHIFT;
        const int pos = base[b] + atomicAdd(&cnt[b], 1);
        const u32 packed = ((u32)(r & (RB - 1)) << 18) | (u32)cols[i];
        svc[pos] = make_float2(vals[i], __uint_as_float(packed));
    }
}

// ===========================================================================
// place_l2: count -> scan -> row_ptr -> place into LDS -> coalesced store.
// (round-21 proven)
// ===========================================================================
__global__ __launch_bounds__(512) void place_l2(
    const int* __restrict__ bkt_ptr, const float2* __restrict__ svc,
    float2* __restrict__ sedge, int* __restrict__ row_ptr)
{
    __shared__ float2 E2[PCAP];
    __shared__ int cnt[RB];
    __shared__ int heads[RB];
    const int b     = blockIdx.x;
    const int rbase = b << RB_SHIFT;
    const int t     = threadIdx.x;

    if (t < RB) cnt[t] = 0;
    __syncthreads();

    const int lo = bkt_ptr[b];
    const int hi = bkt_ptr[b + 1];
    const int n  = hi - lo;

    for (int i = lo + t; i < hi; i += 512)
        atomicAdd(&cnt[__float_as_uint(svc[i].y) >> 18], 1);
    __syncthreads();

    int v = 0;
    if (t < RB) v = cnt[t];
    for (int off = 1; off < RB; off <<= 1) {
        int x = 0;
        if (t < RB && t >= off) x = cnt[t - off];
        __syncthreads();
        if (t < RB) cnt[t] += x;
        __syncthreads();
    }
    if (t < RB) {
        const int excl = cnt[t] - v;
        heads[t] = excl;
        const int gr = rbase + t;
        if (gr <= N_NODES) row_ptr[gr] = lo + excl;
    }
    __syncthreads();

    if (n <= PCAP) {
        for (int i = lo + t; i < hi; i += 512) {
            const float2 vc = svc[i];
            const int lr  = (int)(__float_as_uint(vc.y) >> 18);
            const int pos = atomicAdd(&heads[lr], 1);
            E2[pos] = vc;
        }
        __syncthreads();
        for (int i = t; i < n; i += 512)
            sedge[lo + i] = E2[i];
    } else {
        for (int i = lo + t; i < hi; i += 512) {
            const float2 vc = svc[i];
            const int lr  = (int)(__float_as_uint(vc.y) >> 18);
            const int pos = atomicAdd(&heads[lr], 1);
            sedge[lo + pos] = vc;
        }
    }
}

// ===========================================================================
// FUSED spmm + dense: block = one 16-row tile (256 thr, 4 waves).
// Phase 1: wave w runs the proven per-row pull-spmm loop for rows
//   row0+4w..row0+4w+3, packing bf16 results into LDS trow[16][72].
// Phase 2 (after one barrier): wave w computes the tile's col-quarter
//   c=w via 2x mfma_16x16x32_bf16 + fused epilogue.
// FIRST: reads e0 from ebf, writes e2 -> e2bf (SEPARATE buffer: other
// blocks still gather e0 from ebf - no in-place overwrite), obf partial.
// !FIRST: reads e2bf (gather src), obf; writes final f32 out.
// ===========================================================================
template <bool FIRST>
__global__ __launch_bounds__(256) void fused_stage(
    const int* __restrict__ row_ptr,     // N_NODES+1
    const float2* __restrict__ sedge,    // (val, packed) row-sorted
    const u16* __restrict__ src,         // gather source: FIRST? ebf : e2bf
    const u16* __restrict__ Wbf,         // [64][64] bf16
    const u16* __restrict__ ebf,         // FIRST only: e0 read
    u16* __restrict__ e2bf,              // FIRST only: e2 write
    u16* __restrict__ obf,               // partial mean (bf16)
    float* __restrict__ out)
{
    __shared__ u16 trow[16][72];         // +8 pad: spreads b128 read banks

    const int tid  = threadIdx.x;
    const int lane = tid & 63;
    const int w    = tid >> 6;           // wave 0..3
    const int row0 = blockIdx.x * 16;    // N_NODES = 9375*16 exact

    const int g = lane >> 3;             // edge slot 0..7
    const int q = lane & 7;              // feature octet

    // ---- phase 1: pull-spmm for this wave's 4 rows ----
    #pragma unroll
    for (int rr = 0; rr < 4; ++rr) {
        const int tr  = 4 * w + rr;
        const int row = row0 + tr;
        const int beg = row_ptr[row];
        const int end = row_ptr[row + 1];

        v2f A0 = {0.f, 0.f}, A1 = {0.f, 0.f}, A2 = {0.f, 0.f}, A3 = {0.f, 0.f};

        for (int k = beg; k < end; k += 16) {
            const int  kA  = k + g;
            const int  kB  = k + 8 + g;
            const bool onA = kA < end;
            const bool onB = kB < end;
            const float2 mA = sedge[onA ? kA : end - 1];
            const float2 mB = sedge[onB ? kB : end - 1];
            const float vA = onA ? mA.x : 0.f;
            const float vB = onB ? mB.x : 0.f;
            const u32 iA = __float_as_uint(mA.y) & COL_MASK;
            const u32 iB = __float_as_uint(mB.y) & COL_MASK;
            const uint4 xA = *((const uint4*)(src + (size_t)iA * EMB) + q);
            const uint4 xB = *((const uint4*)(src + (size_t)iB * EMB) + q);
            const v2f vvA = {vA, vA};
            const v2f vvB = {vB, vB};
            A0 = vvA * up2(xA.x) + A0;
            A1 = vvA * up2(xA.y) + A1;
            A2 = vvA * up2(xA.z) + A2;
            A3 = vvA * up2(xA.w) + A3;
            A0 = vvB * up2(xB.x) + A0;
            A1 = vvB * up2(xB.y) + A1;
            A2 = vvB * up2(xB.z) + A2;
            A3 = vvB * up2(xB.w) + A3;
        }

        float s0 = A0.x, s1 = A0.y, s2 = A1.x, s3 = A1.y;
        float s4 = A2.x, s5 = A2.y, s6 = A3.x, s7 = A3.y;
        s0 += __shfl_xor(s0, 8); s0 += __shfl_xor(s0, 16); s0 += __shfl_xor(s0, 32);
        s1 += __shfl_xor(s1, 8); s1 += __shfl_xor(s1, 16); s1 += __shfl_xor(s1, 32);
        s2 += __shfl_xor(s2, 8); s2 += __shfl_xor(s2, 16); s2 += __shfl_xor(s2, 32);
        s3 += __shfl_xor(s3, 8); s3 += __shfl_xor(s3, 16); s3 += __shfl_xor(s3, 32);
        s4 += __shfl_xor(s4, 8); s4 += __shfl_xor(s4, 16); s4 += __shfl_xor(s4, 32);
        s5 += __shfl_xor(s5, 8); s5 += __shfl_xor(s5, 16); s5 += __shfl_xor(s5, 32);
        s6 += __shfl_xor(s6, 8); s6 += __shfl_xor(s6, 16); s6 += __shfl_xor(s6, 32);
        s7 += __shfl_xor(s7, 8); s7 += __shfl_xor(s7, 16); s7 += __shfl_xor(s7, 32);

        if (g == 0) {
            uint4 wv;
            wv.x = pack_bf16(s0, s1);
            wv.y = pack_bf16(s2, s3);
            wv.z = pack_bf16(s4, s5);
            wv.w = pack_bf16(s6, s7);
            *(uint4*)(&trow[tr][8 * q]) = wv;   // 144B row stride, 16B aligned
        }
    }
    __syncthreads();

    // ---- phase 2: dense col-quarter c = w (round-12 proven layout) ----
    const int lr = lane & 15;
    const int lk = lane >> 4;

    const short8v bfrag0 = *(const short8v*)(Wbf + (size_t)(16 * w + lr) * EMB + 8 * lk);
    const short8v bfrag1 = *(const short8v*)(Wbf + (size_t)(16 * w + lr) * EMB + 32 + 8 * lk);
    const short8v afrag0 = *(const short8v*)(&trow[lr][8 * lk]);
    const short8v afrag1 = *(const short8v*)(&trow[lr][32 + 8 * lk]);

    f32x4 acc = {0.f, 0.f, 0.f, 0.f};
    acc = __builtin_amdgcn_mfma_f32_16x16x32_bf16(afrag0, bfrag0, acc, 0, 0, 0);
    acc = __builtin_amdgcn_mfma_f32_16x16x32_bf16(afrag1, bfrag1, acc, 0, 0, 0);

    #pragma unroll
    for (int r = 0; r < 4; ++r) {
        const int row = row0 + 4 * lk + r;
        const size_t idx = (size_t)row * EMB + 16 * w + lr;
        const float e1v = acc[r];
        if (FIRST) {
            const float e2v = (e1v >= 0.f) ? e1v : LEAKY * e1v;
            const float e0v = bf16_lo((u32)ebf[idx]);
            obf[idx]  = f32_to_bf16_rne(0.25f * (e0v + e1v + e2v));
            e2bf[idx] = f32_to_bf16_rne(e2v);
        } else {
            out[idx] = bf16_lo((u32)obf[idx]) + 0.25f * e1v;
        }
    }
}

// ===========================================================================
// Fallback (round-1 proven): atomic SpMM + f32 dense, if ws too small.
// ===========================================================================
__global__ __launch_bounds__(256) void spmm_atomic(
    const float* __restrict__ vals, const int* __restrict__ rows,
    const int* __restrict__ cols, const float* __restrict__ src_a,
    const float* __restrict__ src_b, float* __restrict__ dst)
{
    const int tid  = threadIdx.x;
    const int lane = tid & 63;
    const int e    = blockIdx.x * 4 + (tid >> 6);
    if (e >= N_EDGES) return;
    const float v = vals[e];
    const int   c = cols[e];
    const int   r = rows[e];
    const float* src = (src_b != nullptr && c >= N_USERS)
                           ? src_b + (size_t)(c - N_USERS) * EMB
                           : src_a + (size_t)c * EMB;
    unsafeAtomicAdd(&dst[(size_t)r * EMB + lane], v * src[lane]);
}

template <bool FIRST>
__global__ __launch_bounds__(256) void dense_f32(
    const float* __restrict__ t, const float* __restrict__ W,
    const float* __restrict__ user_emb, const float* __restrict__ item_emb,
    float* __restrict__ e2, float* __restrict__ out)
{
    __shared__ float wT[64][65];
    __shared__ float trow[16][64];

    const int tid = threadIdx.x;
    for (int k = tid; k < 64 * 64; k += 256) {
        const int i = k >> 6, j = k & 63;
        wT[j][i] = W[k];
    }
    const int row_base = blockIdx.x * 16;
    for (int k = tid; k < 16 * 64; k += 256) {
        const int r = k >> 6, j = k & 63;
        const int row = row_base + r;
        trow[r][j] = (row < N_NODES) ? t[(size_t)row * EMB + j] : 0.f;
    }
    __syncthreads();

    const int i  = tid & 63;
    const int r0 = tid >> 6;

    #pragma unroll
    for (int rr = 0; rr < 4; ++rr) {
        const int r   = r0 * 4 + rr;
        const int row = row_base + r;
        if (row >= N_NODES) continue;
        float acc = 0.f;
        #pragma unroll
        for (int j = 0; j < 64; ++j)
            acc = fmaf(trow[r][j], wT[j][i], acc);
        const size_t idx = (size_t)row * EMB + i;
        if (FIRST) {
            const float e1v = acc;
            const float e2v = (e1v >= 0.f) ? e1v : LEAKY * e1v;
            const float e0v = (row < N_USERS)
                                  ? user_emb[idx]
                                  : item_emb[(size_t)(row - N_USERS) * EMB + i];
            e2[idx]  = e2v;
            out[idx] = 0.25f * (e0v + e1v + e2v);
        } else {
            out[idx] += 0.25f * acc;
        }
    }
}

// ===========================================================================
extern "C" void kernel_launch(void* const* d_in, const int* in_sizes, int n_in,
                              void* d_out, int out_size, void* d_ws, size_t ws_size,
                              hipStream_t stream)
{
    const float* user_emb = (const float*)d_in[0];
    const float* item_emb = (const float*)d_in[1];
    const float* W0       = (const float*)d_in[2];
    const float* W1       = (const float*)d_in[3];
    const float* adj_vals = (const float*)d_in[4];
    const int*   adj_rows = (const int*)d_in[5];
    const int*   adj_cols = (const int*)d_in[6];
    float*       out      = (float*)d_out;

    const size_t mat_bytes = (size_t)N_NODES * EMB * sizeof(float);   // 38.4 MB
    const size_t ebf_bytes = (size_t)N_NODES * EMB * sizeof(u16);     // 19.2 MB
    const size_t edge8     = (size_t)N_EDGES * sizeof(float2);        // 19.2 MB
    const size_t hmat      = (size_t)NCH * NBKT * sizeof(int);        // 0.34 MB

    // layout: [svc | e2bf after place] [sedge] [ebf] [obf] [aux] [Wbf]
    const size_t off_svc    = 0;                       // e2bf aliases (svc dead)
    const size_t off_sedge  = off_svc + edge8;
    const size_t off_ebf    = off_sedge + edge8;
    const size_t off_obf    = off_ebf + ebf_bytes;
    const size_t off_rowptr = off_obf + ebf_bytes;
    const size_t off_H      = off_rowptr + (size_t)(N_NODES + 1) * sizeof(int);
    const size_t off_B      = off_H + hmat;
    const size_t off_ptr    = off_B + hmat;
    const size_t off_wbf    = (off_ptr + (size_t)(NBKT + 1) * sizeof(int) + 15) & ~(size_t)15;
    const size_t required   = off_wbf + 2 * (size_t)EMB * EMB * sizeof(u16); // ~79 MB

    const int convh_blocks  = NCH + (N_NODES * EMB / 4 + 1023) / 1024;  // 147+2344

    if (ws_size >= required) {
        float2* svc     = (float2*)((char*)d_ws + off_svc);
        u16*    e2bf    = (u16*)((char*)d_ws + off_svc);    // aliases svc
        float2* sedge   = (float2*)((char*)d_ws + off_sedge);
        u16*    ebf     = (u16*)((char*)d_ws + off_ebf);
        u16*    obf     = (u16*)((char*)d_ws + off_obf);
        int*    row_ptr = (int*)((char*)d_ws + off_rowptr);
        int*    H       = (int*)((char*)d_ws + off_H);
        int*    B       = (int*)((char*)d_ws + off_B);
        int*    bkt_ptr = (int*)((char*)d_ws + off_ptr);
        u16*    Wbf0    = (u16*)((char*)d_ws + off_wbf);
        u16*    Wbf1    = Wbf0 + EMB * EMB;

        // ---- bf16 sources + bucket histogram (one dispatch) ----
        conv_hist<<<convh_blocks, 1024, 0, stream>>>(
            user_emb, item_emb, W0, W1, adj_rows, ebf, Wbf0, Wbf1, H);

        // ---- bucket-sorted edge list + row_ptr (once, reused twice) ----
        scan_fill<<<1, 1024, 0, stream>>>(H, bkt_ptr, B);
        partition_l1<<<NCH, 1024, 0, stream>>>(
            adj_vals, adj_rows, adj_cols, B, svc);
        place_l2<<<NBKT, 512, 0, stream>>>(bkt_ptr, svc, sedge, row_ptr);
        // svc dead from here on -> e2bf owns the region

        // ---- stage 1: spmm(e0) + dense(W0) fused ----
        fused_stage<true><<<NTILE, 256, 0, stream>>>(
            row_ptr, sedge, ebf, Wbf0, ebf, e2bf, obf, out);

        // ---- stage 2: spmm(e2) + dense(W1) fused ----
        fused_stage<false><<<NTILE, 256, 0, stream>>>(
            row_ptr, sedge, e2bf, Wbf1, nullptr, nullptr, obf, out);
    } else {
        // ---- fallback: round-1 atomic path ----
        float* t  = (float*)d_ws;
        float* e2 = (float*)((char*)d_ws + mat_bytes);
        const int dense_blocks = (N_NODES + 15) / 16;

        hipMemsetAsync(t, 0, mat_bytes, stream);
        spmm_atomic<<<(N_EDGES + 3) / 4, 256, 0, stream>>>(
            adj_vals, adj_rows, adj_cols, user_emb, item_emb, t);
        dense_f32<true><<<dense_blocks, 256, 0, stream>>>(
            t, W0, user_emb, item_emb, e2, out);

        hipMemsetAsync(t, 0, mat_bytes, stream);
        spmm_atomic<<<(N_EDGES + 3) / 4, 256, 0, stream>>>(
            adj_vals, adj_rows, adj_cols, e2, nullptr, t);
        dense_f32<false><<<dense_blocks, 256, 0, stream>>>(
            t, W1, nullptr, nullptr, nullptr, out);
    }
}